// Round 1
// baseline (471.354 us; speedup 1.0000x reference)
//
#include <hip/hip_runtime.h>
#include <stdint.h>

// ---------------------------------------------------------------------------
// RPN anchor-target layer for MI355X.
//
// RNG NOTE: implements JAX *partitionable* threefry semantics (default True in
// JAX >= 0.5):
//   split:  key_i = threefry2x32(key; x0=0, x1=i)          (both outputs)
//   bits_i = y0 ^ y1  of threefry2x32(key; x0=0, x1=i)
// If labels mismatch (absmax == 1.0) switch to the ORIGINAL path:
//   split:  counts=iota(2n) halved, out=concat(y0,y1), key_i=(out[2i],out[2i+1])
//   bits:   counts=iota(n) halved, bits=concat(y0,y1)
// ---------------------------------------------------------------------------

#define B_   16
#define A_   9
#define H_   64
#define W_   64
#define HW_  (H_*W_)
#define N_   (HW_*A_)      // 36864
#define KG_  50
#define NBLK_ (N_/256)     // 144 blocks per batch image
#define S0_  (B_*A_*HW_)   // 589824  labels
#define S1_  (B_*4*A_*HW_) // 2359296 targets / in_w / out_w

// base anchors from generate_anchors() (exact: all half-integers cancel)
__constant__ float c_base[A_][4] = {
  { -84.f,  -40.f,  99.f,  55.f},
  {-176.f,  -88.f, 191.f, 103.f},
  {-360.f, -184.f, 375.f, 199.f},
  { -56.f,  -56.f,  71.f,  71.f},
  {-120.f, -120.f, 135.f, 135.f},
  {-248.f, -248.f, 263.f, 263.f},
  { -36.f,  -80.f,  51.f,  95.f},
  { -80.f, -168.f,  95.f, 183.f},
  {-168.f, -344.f, 183.f, 359.f},
};

__device__ __forceinline__ void tf2x32(uint32_t k0, uint32_t k1,
                                       uint32_t x0, uint32_t x1,
                                       uint32_t& o0, uint32_t& o1) {
  const uint32_t ks2 = k0 ^ k1 ^ 0x1BD11BDAu;
  uint32_t ks[3] = {k0, k1, ks2};
  x0 += ks[0]; x1 += ks[1];
  const int R[2][4] = {{13,15,26,6},{17,29,16,24}};
  #pragma unroll
  for (int i = 0; i < 5; i++) {
    #pragma unroll
    for (int j = 0; j < 4; j++) {
      x0 += x1;
      int r = R[i & 1][j];
      x1 = (x1 << r) | (x1 >> (32 - r));
      x1 ^= x0;
    }
    x0 += ks[(i + 1) % 3];
    x1 += ks[(i + 2) % 3] + (uint32_t)(i + 1);
  }
  o0 = x0; o1 = x1;
}

// IoU with explicit non-contracted rounding so k_iou and k_label produce
// bitwise-identical values (is_best uses float equality).
__device__ __forceinline__ float iou_f(float ax1, float ay1, float ax2, float ay2,
                                       float aarea,
                                       float gx1, float gy1, float gx2, float gy2,
                                       float garea) {
  float ix = fmaxf(fminf(ax2, gx2) - fmaxf(ax1, gx1) + 1.f, 0.f);
  float iy = fmaxf(fminf(ay2, gy2) - fmaxf(ay1, gy1) + 1.f, 0.f);
  float inter = __fmul_rn(ix, iy);
  return __fdiv_rn(inter, __fsub_rn(__fadd_rn(aarea, garea), inter));
}

__device__ __forceinline__ float box_area(float x1, float y1, float x2, float y2) {
  return __fmul_rn(__fadd_rn(__fsub_rn(x2, x1), 1.f),
                   __fadd_rn(__fsub_rn(y2, y1), 1.f));
}

__device__ __forceinline__ void anchor_of(int n, float& ax1, float& ay1,
                                          float& ax2, float& ay2) {
  int a = n % A_;
  int loc = n / A_;
  int x = loc % W_;
  int y = loc / W_;
  float sx = 16.f * (float)x, sy = 16.f * (float)y;
  ax1 = c_base[a][0] + sx; ay1 = c_base[a][1] + sy;
  ax2 = c_base[a][2] + sx; ay2 = c_base[a][3] + sy;
}

// ---------------------------------------------------------------------------
// K0: zero gt_max; block 0 derives per-batch threefry keys (foldlike split).
__global__ __launch_bounds__(256) void k_zero(float* __restrict__ gt_max,
                                              uint32_t* __restrict__ keys) {
  int i = blockIdx.x * 256 + threadIdx.x;
  if (i < B_ * KG_) gt_max[i] = 0.f;
  if (blockIdx.x == 0 && threadIdx.x < B_) {
    uint32_t k0, k1, kf0, kf1, kb0, kb1;
    tf2x32(0u, 42u, 0u, (uint32_t)threadIdx.x, k0, k1);  // split(root,16)[b]
    tf2x32(k0, k1, 0u, 0u, kf0, kf1);                    // kf
    tf2x32(k0, k1, 0u, 1u, kb0, kb1);                    // kb
    keys[threadIdx.x * 4 + 0] = kf0;
    keys[threadIdx.x * 4 + 1] = kf1;
    keys[threadIdx.x * 4 + 2] = kb0;
    keys[threadIdx.x * 4 + 3] = kb1;
  }
}

// ---------------------------------------------------------------------------
// K1: per (b,n) IoU vs 50 gts: max_ovr, first-argmax, atomic gt_max (inside).
__global__ __launch_bounds__(256) void k_iou(const float* __restrict__ gtb,
                                             const float* __restrict__ iminfo,
                                             float* __restrict__ max_ovr,
                                             int* __restrict__ amax,
                                             float* __restrict__ gt_max) {
  __shared__ float sgx1[KG_], sgy1[KG_], sgx2[KG_], sgy2[KG_], sga[KG_];
  const int b = blockIdx.x / NBLK_;
  const int chunk = blockIdx.x % NBLK_;
  const int tid = threadIdx.x;
  if (tid < KG_) {
    const float* g = gtb + (b * KG_ + tid) * 5;
    float x1 = g[0], y1 = g[1], x2 = g[2], y2 = g[3];
    sgx1[tid] = x1; sgy1[tid] = y1; sgx2[tid] = x2; sgy2[tid] = y2;
    sga[tid] = box_area(x1, y1, x2, y2);
  }
  __syncthreads();
  const int n = chunk * 256 + tid;
  float ax1, ay1, ax2, ay2;
  anchor_of(n, ax1, ay1, ax2, ay2);
  const float imh = iminfo[0], imw = iminfo[1];
  const bool ins = (ax1 >= 0.f) && (ay1 >= 0.f) && (ax2 < imw) && (ay2 < imh);
  const float aarea = box_area(ax1, ay1, ax2, ay2);
  float best = -1.f;
  int bidx = 0;
  for (int k = 0; k < KG_; k++) {
    float ovr = iou_f(ax1, ay1, ax2, ay2, aarea,
                      sgx1[k], sgy1[k], sgx2[k], sgy2[k], sga[k]);
    if (ovr > best) { best = ovr; bidx = k; }
    float v = ins ? ovr : 0.f;   // ovr_in
    v = fmaxf(v, __shfl_xor(v, 32));
    v = fmaxf(v, __shfl_xor(v, 16));
    v = fmaxf(v, __shfl_xor(v, 8));
    v = fmaxf(v, __shfl_xor(v, 4));
    v = fmaxf(v, __shfl_xor(v, 2));
    v = fmaxf(v, __shfl_xor(v, 1));
    if ((tid & 63) == 0 && v > 0.f)
      atomicMax((int*)(gt_max + b * KG_ + k), __float_as_int(v));  // v>=0 -> int order ok
  }
  max_ovr[(size_t)b * N_ + n] = best;
  amax[(size_t)b * N_ + n] = bidx;
}

// ---------------------------------------------------------------------------
// K2: labels (is_best via exact recompute + float equality) + prio generation.
__global__ __launch_bounds__(256) void k_label(const float* __restrict__ gtb,
                                               const float* __restrict__ iminfo,
                                               const float* __restrict__ max_ovr,
                                               const float* __restrict__ gt_max,
                                               const uint32_t* __restrict__ keys,
                                               float* __restrict__ lbl,
                                               uint32_t* __restrict__ priof,
                                               uint32_t* __restrict__ priob) {
  __shared__ float sgx1[KG_], sgy1[KG_], sgx2[KG_], sgy2[KG_], sga[KG_], sgm[KG_];
  const int b = blockIdx.x / NBLK_;
  const int chunk = blockIdx.x % NBLK_;
  const int tid = threadIdx.x;
  if (tid < KG_) {
    const float* g = gtb + (b * KG_ + tid) * 5;
    float x1 = g[0], y1 = g[1], x2 = g[2], y2 = g[3];
    sgx1[tid] = x1; sgy1[tid] = y1; sgx2[tid] = x2; sgy2[tid] = y2;
    sga[tid] = box_area(x1, y1, x2, y2);
    float gm = gt_max[b * KG_ + tid];
    sgm[tid] = (gm == 0.f) ? 1e-5f : gm;
  }
  __syncthreads();
  const int n = chunk * 256 + tid;
  float ax1, ay1, ax2, ay2;
  anchor_of(n, ax1, ay1, ax2, ay2);
  const float imh = iminfo[0], imw = iminfo[1];
  const bool ins = (ax1 >= 0.f) && (ay1 >= 0.f) && (ax2 < imw) && (ay2 < imh);
  const float aarea = box_area(ax1, ay1, ax2, ay2);
  bool best = false;
  for (int k = 0; k < KG_; k++) {
    float ovr = iou_f(ax1, ay1, ax2, ay2, aarea,
                      sgx1[k], sgy1[k], sgx2[k], sgy2[k], sga[k]);
    best = best || (ovr == sgm[k]);
  }
  const float mo = max_ovr[(size_t)b * N_ + n];
  float l = -1.f;
  if (ins) {
    if (mo < 0.3f) l = 0.f;
    if (best || mo >= 0.7f) l = 1.f;
  }
  lbl[(size_t)b * N_ + n] = l;
  // priorities: uniform = m * 2^-23 with m = (y0^y1) >> 9 (partitionable path)
  uint32_t y0, y1;
  tf2x32(keys[b * 4 + 0], keys[b * 4 + 1], 0u, (uint32_t)n, y0, y1);
  priof[(size_t)b * N_ + n] = (y0 ^ y1) >> 9;
  tf2x32(keys[b * 4 + 2], keys[b * 4 + 3], 0u, (uint32_t)n, y0, y1);
  priob[(size_t)b * N_ + n] = (y0 ^ y1) >> 9;
}

// ---------------------------------------------------------------------------
// K3: per-batch subsample. Exactly matches stable argsort(-prio) + rank>=limit:
// keep top-`limit` by (m desc, index asc). 3-level histogram select on 23-bit m.
__global__ __launch_bounds__(256) void k_sub(float* __restrict__ lbl,
                                             const uint32_t* __restrict__ priof,
                                             const uint32_t* __restrict__ priob,
                                             float* __restrict__ uw) {
  const int b = blockIdx.x;
  const int tid = threadIdx.x;
  __shared__ uint32_t sh_hist[256];
  __shared__ uint32_t sh_scan[256];
  __shared__ int sh_M;
  __shared__ int sh_bin, sh_rem;
  __shared__ int sh_eqlist[64];
  __shared__ int sh_eqn;

  float* L = lbl + (size_t)b * N_;
  int fg_kept = 0, bg_kept = 0;

  for (int phase = 0; phase < 2; phase++) {
    const float maskv = (phase == 0) ? 1.f : 0.f;
    const int limit = (phase == 0) ? 128 : (256 - fg_kept);
    const uint32_t* P = ((phase == 0) ? priof : priob) + (size_t)b * N_;

    if (tid == 0) sh_M = 0;
    __syncthreads();
    int cnt = 0;
    for (int i = tid; i < N_; i += 256)
      if (L[i] == maskv) cnt++;
    atomicAdd(&sh_M, cnt);
    __syncthreads();
    const int M = sh_M;
    int kept;
    if (M <= limit) {
      kept = M;                       // nothing disabled
    } else {
      kept = limit;
      int r = limit;
      int H1 = 0, H2 = 0, H3 = 0;
      uint32_t hi_prefix = 0;
      for (int lev = 0; lev < 3; lev++) {
        sh_hist[tid] = 0;
        __syncthreads();
        for (int i = tid; i < N_; i += 256) {
          if (L[i] == maskv) {
            uint32_t m = P[i];
            int bin; bool ok;
            if (lev == 0)      { bin = (int)(m >> 15);        ok = true; }
            else if (lev == 1) { bin = (int)((m >> 7) & 255u); ok = ((m >> 15) == (uint32_t)H1); }
            else               { bin = (int)(m & 127u);        ok = ((m >> 7) == hi_prefix); }
            if (ok) atomicAdd(&sh_hist[bin], 1u);
          }
        }
        __syncthreads();
        sh_scan[tid] = sh_hist[tid];
        __syncthreads();
        for (int off = 1; off < 256; off <<= 1) {  // suffix sum (Hillis-Steele)
          uint32_t v = (tid + off < 256) ? sh_scan[tid + off] : 0u;
          __syncthreads();
          sh_scan[tid] += v;
          __syncthreads();
        }
        uint32_t incl = sh_scan[tid];
        uint32_t excl = incl - sh_hist[tid];
        if (incl >= (uint32_t)r && excl < (uint32_t)r) {
          sh_bin = tid;
          sh_rem = r - (int)excl;
        }
        __syncthreads();
        int Hl = sh_bin; r = sh_rem;
        if (lev == 0)      { H1 = Hl; }
        else if (lev == 1) { H2 = Hl; hi_prefix = ((uint32_t)H1 << 8) | (uint32_t)H2; }
        else               { H3 = Hl; }
        __syncthreads();
      }
      const uint32_t t = ((uint32_t)H1 << 15) | ((uint32_t)H2 << 7) | (uint32_t)H3;
      const int keep_eq = r;                   // # of value-t elems kept (by index)
      const int eq_total = (int)sh_hist[H3];
      const bool partial = keep_eq < eq_total; // boundary tie (rare)
      if (partial) {
        if (tid == 0) sh_eqn = 0;
        __syncthreads();
        for (int i = tid; i < N_; i += 256)
          if (L[i] == maskv && P[i] == t) {
            int p = atomicAdd(&sh_eqn, 1);
            if (p < 64) sh_eqlist[p] = i;
          }
        __syncthreads();
      }
      const int eqn = partial ? min(sh_eqn, 64) : 0;
      for (int i = tid; i < N_; i += 256) {
        if (L[i] == maskv) {
          uint32_t m = P[i];
          if (m < t) {
            L[i] = -1.f;
          } else if (m == t && partial) {
            int rk = 0;
            for (int j = 0; j < eqn; j++)
              if (sh_eqlist[j] < i) rk++;
            if (rk >= keep_eq) L[i] = -1.f;
          }
        }
      }
      __syncthreads();
    }
    if (phase == 0) fg_kept = kept; else bg_kept = kept;
    __syncthreads();
  }
  if (tid == 0) uw[b] = 1.f / (float)(fg_kept + bg_kept);
}

// ---------------------------------------------------------------------------
// K4: write all outputs in the transposed (B,C,H,W) layouts, coalesced in w.
__global__ __launch_bounds__(256) void k_out(const float* __restrict__ gtb,
                                             const float* __restrict__ iminfo,
                                             const float* __restrict__ lbl,
                                             const int* __restrict__ amax,
                                             const float* __restrict__ uw,
                                             float* __restrict__ out) {
  const int t = blockIdx.x * 256 + threadIdx.x;  // 0 .. S0_-1 exactly
  const int w = t & 63;
  const int h = (t >> 6) & 63;
  const int a = (t >> 12) % A_;
  const int b = t / (A_ * HW_);
  const int n = (h * W_ + w) * A_ + a;

  const float ax1 = c_base[a][0] + 16.f * (float)w;
  const float ay1 = c_base[a][1] + 16.f * (float)h;
  const float ax2 = c_base[a][2] + 16.f * (float)w;
  const float ay2 = c_base[a][3] + 16.f * (float)h;
  const float imh = iminfo[0], imw = iminfo[1];
  const bool ins = (ax1 >= 0.f) && (ay1 >= 0.f) && (ax2 < imw) && (ay2 < imh);

  const float l = lbl[(size_t)b * N_ + n];

  // labels: (B,1,A*H,W)
  out[(size_t)b * (A_ * HW_) + a * HW_ + h * W_ + w] = ins ? l : 0.f;

  // targets
  float tx = 0.f, ty = 0.f, tw = 0.f, th = 0.f;
  if (ins) {
    const int g = amax[(size_t)b * N_ + n];
    const float* gp = gtb + ((size_t)b * KG_ + g) * 5;
    float aw = ax2 - ax1 + 1.f, ah = ay2 - ay1 + 1.f;
    float acx = ax1 + 0.5f * (aw - 1.f), acy = ay1 + 0.5f * (ah - 1.f);
    float gw = gp[2] - gp[0] + 1.f, gh = gp[3] - gp[1] + 1.f;
    float gcx = gp[0] + 0.5f * (gw - 1.f), gcy = gp[1] + 0.5f * (gh - 1.f);
    tx = (gcx - acx) / aw;
    ty = (gcy - acy) / ah;
    tw = logf(gw / aw);
    th = logf(gh / ah);
  }
  float* o1 = out + S0_;
  const size_t toff = (size_t)b * (4 * A_ * HW_) + (4 * a) * HW_ + h * W_ + w;
  o1[toff]           = tx;
  o1[toff + HW_]     = ty;
  o1[toff + 2 * HW_] = tw;
  o1[toff + 3 * HW_] = th;

  const float inw = (ins && l == 1.f) ? 1.f : 0.f;
  const float oww = (ins && (l == 0.f || l == 1.f)) ? uw[b] : 0.f;
  float* o2 = out + S0_ + S1_;
  o2[toff] = inw; o2[toff + HW_] = inw; o2[toff + 2 * HW_] = inw; o2[toff + 3 * HW_] = inw;
  float* o3 = out + S0_ + 2 * (size_t)S1_;
  o3[toff] = oww; o3[toff + HW_] = oww; o3[toff + 2 * HW_] = oww; o3[toff + 3 * HW_] = oww;
}

// ---------------------------------------------------------------------------
extern "C" void kernel_launch(void* const* d_in, const int* in_sizes, int n_in,
                              void* d_out, int out_size, void* d_ws, size_t ws_size,
                              hipStream_t stream) {
  const float* gtb = (const float*)d_in[1];     // gt_boxes (B,50,5)
  const float* iminfo = (const float*)d_in[2];  // im_info  (B,2)
  float* out = (float*)d_out;

  // workspace layout (~11.8 MB)
  float* lbl = (float*)d_ws;                       // B*N
  float* max_ovr = lbl + (size_t)B_ * N_;          // B*N
  int* amax = (int*)(max_ovr + (size_t)B_ * N_);   // B*N
  float* gt_max = (float*)(amax + (size_t)B_ * N_);// B*KG
  float* uw = gt_max + B_ * KG_;                   // B
  uint32_t* keys = (uint32_t*)(uw + B_);           // B*4
  uint32_t* priof = keys + B_ * 4;                 // B*N
  uint32_t* priob = priof + (size_t)B_ * N_;       // B*N

  k_zero<<<4, 256, 0, stream>>>(gt_max, keys);
  k_iou<<<B_ * NBLK_, 256, 0, stream>>>(gtb, iminfo, max_ovr, amax, gt_max);
  k_label<<<B_ * NBLK_, 256, 0, stream>>>(gtb, iminfo, max_ovr, gt_max, keys,
                                          lbl, priof, priob);
  k_sub<<<B_, 256, 0, stream>>>(lbl, priof, priob, uw);
  k_out<<<S0_ / 256, 256, 0, stream>>>(gtb, iminfo, lbl, amax, uw, out);
}

// Round 3
// 300.849 us; speedup vs baseline: 1.5667x; 1.5667x over previous
//
#include <hip/hip_runtime.h>
#include <stdint.h>

// ---------------------------------------------------------------------------
// RPN anchor-target layer for MI355X — round 3 (bisect round).
// Round-1-verbatim: k_zero, k_iou, k_label, k_out  (bit-exact verified R1).
// New (under test): k_sub2 — single-level hist + in-bin composite-key cutoff,
// in-place disable on lbl.  Composite key = (m<<16)|(65535-n), keys distinct.
// ---------------------------------------------------------------------------

#define B_   16
#define A_   9
#define H_   64
#define W_   64
#define HW_  (H_*W_)
#define N_   (HW_*A_)      // 36864
#define KG_  50
#define NBLK_ (N_/256)     // 144 blocks per batch image
#define S0_  (B_*A_*HW_)   // labels elems
#define S1_  (B_*4*A_*HW_) // targets / in_w / out_w elems

// base anchors from generate_anchors() (exact: all half-integers cancel)
__constant__ float c_base[A_][4] = {
  { -84.f,  -40.f,  99.f,  55.f},
  {-176.f,  -88.f, 191.f, 103.f},
  {-360.f, -184.f, 375.f, 199.f},
  { -56.f,  -56.f,  71.f,  71.f},
  {-120.f, -120.f, 135.f, 135.f},
  {-248.f, -248.f, 263.f, 263.f},
  { -36.f,  -80.f,  51.f,  95.f},
  { -80.f, -168.f,  95.f, 183.f},
  {-168.f, -344.f, 183.f, 359.f},
};

__device__ __forceinline__ void tf2x32(uint32_t k0, uint32_t k1,
                                       uint32_t x0, uint32_t x1,
                                       uint32_t& o0, uint32_t& o1) {
  const uint32_t ks2 = k0 ^ k1 ^ 0x1BD11BDAu;
  uint32_t ks[3] = {k0, k1, ks2};
  x0 += ks[0]; x1 += ks[1];
  const int R[2][4] = {{13,15,26,6},{17,29,16,24}};
  #pragma unroll
  for (int i = 0; i < 5; i++) {
    #pragma unroll
    for (int j = 0; j < 4; j++) {
      x0 += x1;
      int r = R[i & 1][j];
      x1 = (x1 << r) | (x1 >> (32 - r));
      x1 ^= x0;
    }
    x0 += ks[(i + 1) % 3];
    x1 += ks[(i + 2) % 3] + (uint32_t)(i + 1);
  }
  o0 = x0; o1 = x1;
}

// IoU with explicit non-contracted rounding so k_iou and k_label produce
// bitwise-identical values (is_best uses float equality).
__device__ __forceinline__ float iou_f(float ax1, float ay1, float ax2, float ay2,
                                       float aarea,
                                       float gx1, float gy1, float gx2, float gy2,
                                       float garea) {
  float ix = fmaxf(fminf(ax2, gx2) - fmaxf(ax1, gx1) + 1.f, 0.f);
  float iy = fmaxf(fminf(ay2, gy2) - fmaxf(ay1, gy1) + 1.f, 0.f);
  float inter = __fmul_rn(ix, iy);
  return __fdiv_rn(inter, __fsub_rn(__fadd_rn(aarea, garea), inter));
}

__device__ __forceinline__ float box_area(float x1, float y1, float x2, float y2) {
  return __fmul_rn(__fadd_rn(__fsub_rn(x2, x1), 1.f),
                   __fadd_rn(__fsub_rn(y2, y1), 1.f));
}

__device__ __forceinline__ void anchor_of(int n, float& ax1, float& ay1,
                                          float& ax2, float& ay2) {
  int a = n % A_;
  int loc = n / A_;
  int x = loc % W_;
  int y = loc / W_;
  float sx = 16.f * (float)x, sy = 16.f * (float)y;
  ax1 = c_base[a][0] + sx; ay1 = c_base[a][1] + sy;
  ax2 = c_base[a][2] + sx; ay2 = c_base[a][3] + sy;
}

// ---------------------------------------------------------------------------
// K0 (R1 verbatim): zero gt_max; block 0 derives per-batch threefry keys.
__global__ __launch_bounds__(256) void k_zero(float* __restrict__ gt_max,
                                              uint32_t* __restrict__ keys) {
  int i = blockIdx.x * 256 + threadIdx.x;
  if (i < B_ * KG_) gt_max[i] = 0.f;
  if (blockIdx.x == 0 && threadIdx.x < B_) {
    uint32_t k0, k1, kf0, kf1, kb0, kb1;
    tf2x32(0u, 42u, 0u, (uint32_t)threadIdx.x, k0, k1);  // split(root,16)[b]
    tf2x32(k0, k1, 0u, 0u, kf0, kf1);                    // kf
    tf2x32(k0, k1, 0u, 1u, kb0, kb1);                    // kb
    keys[threadIdx.x * 4 + 0] = kf0;
    keys[threadIdx.x * 4 + 1] = kf1;
    keys[threadIdx.x * 4 + 2] = kb0;
    keys[threadIdx.x * 4 + 3] = kb1;
  }
}

// ---------------------------------------------------------------------------
// K1 (R1 verbatim): per (b,n) IoU vs 50 gts: max_ovr, first-argmax, gt_max.
__global__ __launch_bounds__(256) void k_iou(const float* __restrict__ gtb,
                                             const float* __restrict__ iminfo,
                                             float* __restrict__ max_ovr,
                                             int* __restrict__ amax,
                                             float* __restrict__ gt_max) {
  __shared__ float sgx1[KG_], sgy1[KG_], sgx2[KG_], sgy2[KG_], sga[KG_];
  const int b = blockIdx.x / NBLK_;
  const int chunk = blockIdx.x % NBLK_;
  const int tid = threadIdx.x;
  if (tid < KG_) {
    const float* g = gtb + (b * KG_ + tid) * 5;
    float x1 = g[0], y1 = g[1], x2 = g[2], y2 = g[3];
    sgx1[tid] = x1; sgy1[tid] = y1; sgx2[tid] = x2; sgy2[tid] = y2;
    sga[tid] = box_area(x1, y1, x2, y2);
  }
  __syncthreads();
  const int n = chunk * 256 + tid;
  float ax1, ay1, ax2, ay2;
  anchor_of(n, ax1, ay1, ax2, ay2);
  const float imh = iminfo[0], imw = iminfo[1];
  const bool ins = (ax1 >= 0.f) && (ay1 >= 0.f) && (ax2 < imw) && (ay2 < imh);
  const float aarea = box_area(ax1, ay1, ax2, ay2);
  float best = -1.f;
  int bidx = 0;
  for (int k = 0; k < KG_; k++) {
    float ovr = iou_f(ax1, ay1, ax2, ay2, aarea,
                      sgx1[k], sgy1[k], sgx2[k], sgy2[k], sga[k]);
    if (ovr > best) { best = ovr; bidx = k; }
    float v = ins ? ovr : 0.f;   // ovr_in
    v = fmaxf(v, __shfl_xor(v, 32));
    v = fmaxf(v, __shfl_xor(v, 16));
    v = fmaxf(v, __shfl_xor(v, 8));
    v = fmaxf(v, __shfl_xor(v, 4));
    v = fmaxf(v, __shfl_xor(v, 2));
    v = fmaxf(v, __shfl_xor(v, 1));
    if ((tid & 63) == 0 && v > 0.f)
      atomicMax((int*)(gt_max + b * KG_ + k), __float_as_int(v));  // v>=0 -> int order ok
  }
  max_ovr[(size_t)b * N_ + n] = best;
  amax[(size_t)b * N_ + n] = bidx;
}

// ---------------------------------------------------------------------------
// K2 (R1 verbatim): labels + prio generation.
__global__ __launch_bounds__(256) void k_label(const float* __restrict__ gtb,
                                               const float* __restrict__ iminfo,
                                               const float* __restrict__ max_ovr,
                                               const float* __restrict__ gt_max,
                                               const uint32_t* __restrict__ keys,
                                               float* __restrict__ lbl,
                                               uint32_t* __restrict__ priof,
                                               uint32_t* __restrict__ priob) {
  __shared__ float sgx1[KG_], sgy1[KG_], sgx2[KG_], sgy2[KG_], sga[KG_], sgm[KG_];
  const int b = blockIdx.x / NBLK_;
  const int chunk = blockIdx.x % NBLK_;
  const int tid = threadIdx.x;
  if (tid < KG_) {
    const float* g = gtb + (b * KG_ + tid) * 5;
    float x1 = g[0], y1 = g[1], x2 = g[2], y2 = g[3];
    sgx1[tid] = x1; sgy1[tid] = y1; sgx2[tid] = x2; sgy2[tid] = y2;
    sga[tid] = box_area(x1, y1, x2, y2);
    float gm = gt_max[b * KG_ + tid];
    sgm[tid] = (gm == 0.f) ? 1e-5f : gm;
  }
  __syncthreads();
  const int n = chunk * 256 + tid;
  float ax1, ay1, ax2, ay2;
  anchor_of(n, ax1, ay1, ax2, ay2);
  const float imh = iminfo[0], imw = iminfo[1];
  const bool ins = (ax1 >= 0.f) && (ay1 >= 0.f) && (ax2 < imw) && (ay2 < imh);
  const float aarea = box_area(ax1, ay1, ax2, ay2);
  bool best = false;
  for (int k = 0; k < KG_; k++) {
    float ovr = iou_f(ax1, ay1, ax2, ay2, aarea,
                      sgx1[k], sgy1[k], sgx2[k], sgy2[k], sga[k]);
    best = best || (ovr == sgm[k]);
  }
  const float mo = max_ovr[(size_t)b * N_ + n];
  float l = -1.f;
  if (ins) {
    if (mo < 0.3f) l = 0.f;
    if (best || mo >= 0.7f) l = 1.f;
  }
  lbl[(size_t)b * N_ + n] = l;
  // priorities: uniform = m * 2^-23 with m = (y0^y1) >> 9 (partitionable path)
  uint32_t y0, y1;
  tf2x32(keys[b * 4 + 0], keys[b * 4 + 1], 0u, (uint32_t)n, y0, y1);
  priof[(size_t)b * N_ + n] = (y0 ^ y1) >> 9;
  tf2x32(keys[b * 4 + 2], keys[b * 4 + 3], 0u, (uint32_t)n, y0, y1);
  priob[(size_t)b * N_ + n] = (y0 ^ y1) >> 9;
}

// ---------------------------------------------------------------------------
// K3 (NEW, under test): per-batch subsample, in-place on lbl.
// keep top-`limit` by composite key (m<<16 | (65535-i)); 1-level hist on
// m>>15 + serial bin pick + in-bin gather + parallel rank -> cutoff K*.
__global__ __launch_bounds__(256) void k_sub2(float* __restrict__ lbl,
                                              const uint32_t* __restrict__ priof,
                                              const uint32_t* __restrict__ priob,
                                              float* __restrict__ uw) {
  const int b = blockIdx.x;
  const int tid = threadIdx.x;
  __shared__ int sh_hist[256];
  __shared__ int sh_cnt;
  __shared__ int sh_bin, sh_r, s_n;
  __shared__ unsigned long long s_keys[2048];
  __shared__ unsigned long long sh_kstar;

  float* L = lbl + (size_t)b * N_;
  int fg_kept = 0, bg_kept = 0;

  for (int phase = 0; phase < 2; phase++) {
    const float maskv = (phase == 0) ? 1.f : 0.f;
    const int limit = (phase == 0) ? 128 : (256 - fg_kept);
    const uint32_t* P = ((phase == 0) ? priof : priob) + (size_t)b * N_;
    const float4* L4 = (const float4*)L;
    const uint4* P4 = (const uint4*)P;

    // pass 1: count masked
    if (tid == 0) sh_cnt = 0;
    __syncthreads();
    int c0 = 0;
    for (int i4 = tid; i4 < N_ / 4; i4 += 256) {
      float4 v = L4[i4];
      c0 += (v.x == maskv) + (v.y == maskv) + (v.z == maskv) + (v.w == maskv);
    }
    atomicAdd(&sh_cnt, c0);
    __syncthreads();
    const int M = sh_cnt;

    if (M > limit) {
      // pass 2: 256-bin hist of m>>15 over masked elems
      sh_hist[tid] = 0;
      __syncthreads();
      for (int i4 = tid; i4 < N_ / 4; i4 += 256) {
        float4 v = L4[i4];
        uint4 m4 = P4[i4];
        if (v.x == maskv) atomicAdd(&sh_hist[m4.x >> 15], 1);
        if (v.y == maskv) atomicAdd(&sh_hist[m4.y >> 15], 1);
        if (v.z == maskv) atomicAdd(&sh_hist[m4.z >> 15], 1);
        if (v.w == maskv) atomicAdd(&sh_hist[m4.w >> 15], 1);
      }
      __syncthreads();
      // serial bin pick (thread 0): descending bins until cumulative >= limit
      if (tid == 0) {
        int acc = 0, bin = 255;
        for (; bin > 0; bin--) {
          if (acc + sh_hist[bin] >= limit) break;
          acc += sh_hist[bin];
        }
        sh_bin = bin;
        sh_r = limit - acc;   // rank within bin, 1-based, in [1, hist[bin]]
        s_n = 0;
      }
      __syncthreads();
      const int bin0 = sh_bin, r0 = sh_r;
      // pass 3: gather this bin's composite keys
      for (int i4 = tid; i4 < N_ / 4; i4 += 256) {
        float4 v = L4[i4];
        uint4 m4 = P4[i4];
        const float lv[4] = {v.x, v.y, v.z, v.w};
        const uint32_t mv[4] = {m4.x, m4.y, m4.z, m4.w};
        #pragma unroll
        for (int j = 0; j < 4; j++) {
          if (lv[j] == maskv && (int)(mv[j] >> 15) == bin0) {
            int pos = atomicAdd(&s_n, 1);
            if (pos < 2048)
              s_keys[pos] = ((unsigned long long)mv[j] << 16) |
                            (unsigned long long)(65535 - (i4 * 4 + j));
          }
        }
      }
      __syncthreads();
      const int s = min(s_n, 2048);
      // parallel rank: K* = r0-th largest key in bin (keys distinct)
      for (int j = tid; j < s; j += 256) {
        unsigned long long kj = s_keys[j];
        int rank = 0;
        for (int q = 0; q < s; q++) rank += (s_keys[q] > kj) ? 1 : 0;
        if (rank == r0 - 1) sh_kstar = kj;
      }
      __syncthreads();
      const unsigned long long Kst = sh_kstar;
      // pass 4: disable key < K*
      for (int i4 = tid; i4 < N_ / 4; i4 += 256) {
        float4 v = L4[i4];
        uint4 m4 = P4[i4];
        const float lv[4] = {v.x, v.y, v.z, v.w};
        const uint32_t mv[4] = {m4.x, m4.y, m4.z, m4.w};
        #pragma unroll
        for (int j = 0; j < 4; j++) {
          if (lv[j] == maskv) {
            unsigned long long key = ((unsigned long long)mv[j] << 16) |
                                     (unsigned long long)(65535 - (i4 * 4 + j));
            if (key < Kst) L[i4 * 4 + j] = -1.f;
          }
        }
      }
    }
    __syncthreads();
    const int kept = (M <= limit) ? M : limit;
    if (phase == 0) fg_kept = kept; else bg_kept = kept;
    __syncthreads();
  }
  if (tid == 0) uw[b] = 1.f / (float)(fg_kept + bg_kept);
}

// ---------------------------------------------------------------------------
// K4 (R1 verbatim): write all outputs in transposed layouts, coalesced in w.
__global__ __launch_bounds__(256) void k_out(const float* __restrict__ gtb,
                                             const float* __restrict__ iminfo,
                                             const float* __restrict__ lbl,
                                             const int* __restrict__ amax,
                                             const float* __restrict__ uw,
                                             float* __restrict__ out) {
  const int t = blockIdx.x * 256 + threadIdx.x;  // 0 .. S0_-1 exactly
  const int w = t & 63;
  const int h = (t >> 6) & 63;
  const int a = (t >> 12) % A_;
  const int b = t / (A_ * HW_);
  const int n = (h * W_ + w) * A_ + a;

  const float ax1 = c_base[a][0] + 16.f * (float)w;
  const float ay1 = c_base[a][1] + 16.f * (float)h;
  const float ax2 = c_base[a][2] + 16.f * (float)w;
  const float ay2 = c_base[a][3] + 16.f * (float)h;
  const float imh = iminfo[0], imw = iminfo[1];
  const bool ins = (ax1 >= 0.f) && (ay1 >= 0.f) && (ax2 < imw) && (ay2 < imh);

  const float l = lbl[(size_t)b * N_ + n];

  // labels: (B,1,A*H,W)
  out[(size_t)b * (A_ * HW_) + a * HW_ + h * W_ + w] = ins ? l : 0.f;

  // targets
  float tx = 0.f, ty = 0.f, tw = 0.f, th = 0.f;
  if (ins) {
    const int g = amax[(size_t)b * N_ + n];
    const float* gp = gtb + ((size_t)b * KG_ + g) * 5;
    float aw = ax2 - ax1 + 1.f, ah = ay2 - ay1 + 1.f;
    float acx = ax1 + 0.5f * (aw - 1.f), acy = ay1 + 0.5f * (ah - 1.f);
    float gw = gp[2] - gp[0] + 1.f, gh = gp[3] - gp[1] + 1.f;
    float gcx = gp[0] + 0.5f * (gw - 1.f), gcy = gp[1] + 0.5f * (gh - 1.f);
    tx = (gcx - acx) / aw;
    ty = (gcy - acy) / ah;
    tw = logf(gw / aw);
    th = logf(gh / ah);
  }
  float* o1 = out + S0_;
  const size_t toff = (size_t)b * (4 * A_ * HW_) + (4 * a) * HW_ + h * W_ + w;
  o1[toff]           = tx;
  o1[toff + HW_]     = ty;
  o1[toff + 2 * HW_] = tw;
  o1[toff + 3 * HW_] = th;

  const float inw = (ins && l == 1.f) ? 1.f : 0.f;
  const float oww = (ins && (l == 0.f || l == 1.f)) ? uw[b] : 0.f;
  float* o2 = out + S0_ + S1_;
  o2[toff] = inw; o2[toff + HW_] = inw; o2[toff + 2 * HW_] = inw; o2[toff + 3 * HW_] = inw;
  float* o3 = out + S0_ + 2 * (size_t)S1_;
  o3[toff] = oww; o3[toff + HW_] = oww; o3[toff + 2 * HW_] = oww; o3[toff + 3 * HW_] = oww;
}

// ---------------------------------------------------------------------------
extern "C" void kernel_launch(void* const* d_in, const int* in_sizes, int n_in,
                              void* d_out, int out_size, void* d_ws, size_t ws_size,
                              hipStream_t stream) {
  const float* gtb = (const float*)d_in[1];     // gt_boxes (B,50,5)
  const float* iminfo = (const float*)d_in[2];  // im_info  (B,2)
  float* out = (float*)d_out;

  // workspace layout (~11.8 MB, same as round 1)
  float* lbl = (float*)d_ws;                       // B*N
  float* max_ovr = lbl + (size_t)B_ * N_;          // B*N
  int* amax = (int*)(max_ovr + (size_t)B_ * N_);   // B*N
  float* gt_max = (float*)(amax + (size_t)B_ * N_);// B*KG
  float* uw = gt_max + B_ * KG_;                   // B
  uint32_t* keys = (uint32_t*)(uw + B_);           // B*4
  uint32_t* priof = keys + B_ * 4;                 // B*N
  uint32_t* priob = priof + (size_t)B_ * N_;       // B*N

  k_zero<<<4, 256, 0, stream>>>(gt_max, keys);
  k_iou<<<B_ * NBLK_, 256, 0, stream>>>(gtb, iminfo, max_ovr, amax, gt_max);
  k_label<<<B_ * NBLK_, 256, 0, stream>>>(gtb, iminfo, max_ovr, gt_max, keys,
                                          lbl, priof, priob);
  k_sub2<<<B_, 256, 0, stream>>>(lbl, priof, priob, uw);
  k_out<<<S0_ / 256, 256, 0, stream>>>(gtb, iminfo, lbl, amax, uw, out);
}

// Round 6
// 254.970 us; speedup vs baseline: 1.8487x; 1.1799x over previous
//
#include <hip/hip_runtime.h>
#include <stdint.h>

// ---------------------------------------------------------------------------
// RPN anchor-target layer for MI355X — round 6.
//
// KEY FIX vs R5: is_best requires bitwise equality between IoU computed in
// the gt_max pass and the label pass. Per-kernel FP codegen (ffp-contract)
// made structurally-different kernels produce different bits (R2/R4/R5 all
// failed at absmax 2.0). iou_pair is now ONE noinline function — a single
// compiled copy shared by k_gtmax and k_fuse — with contract(off) inside.
// Bit-consistency by construction, independent of compiler flags.
//
//  * k_init:  per-batch threefry keys
//  * k_gtmax: one block per (b,gt), block fmax reduce, direct store
//  * k_fuse:  single 50-IoU loop -> lbl, amax, priof, priob
//  * k_sub2:  R3-VERBATIM verified subsample
//  * k_out:   R3-VERBATIM output writer
// ---------------------------------------------------------------------------

#define B_   16
#define A_   9
#define H_   64
#define W_   64
#define HW_  (H_*W_)
#define N_   (HW_*A_)      // 36864
#define KG_  50
#define NBLK_ (N_/256)     // 144 blocks per batch image
#define S0_  (B_*A_*HW_)   // labels elems
#define S1_  (B_*4*A_*HW_) // targets / in_w / out_w elems

// base anchors from generate_anchors() (exact: all half-integers cancel)
__constant__ float c_base[A_][4] = {
  { -84.f,  -40.f,  99.f,  55.f},
  {-176.f,  -88.f, 191.f, 103.f},
  {-360.f, -184.f, 375.f, 199.f},
  { -56.f,  -56.f,  71.f,  71.f},
  {-120.f, -120.f, 135.f, 135.f},
  {-248.f, -248.f, 263.f, 263.f},
  { -36.f,  -80.f,  51.f,  95.f},
  { -80.f, -168.f,  95.f, 183.f},
  {-168.f, -344.f, 183.f, 359.f},
};

__device__ __forceinline__ void tf2x32(uint32_t k0, uint32_t k1,
                                       uint32_t x0, uint32_t x1,
                                       uint32_t& o0, uint32_t& o1) {
  const uint32_t ks2 = k0 ^ k1 ^ 0x1BD11BDAu;
  uint32_t ks[3] = {k0, k1, ks2};
  x0 += ks[0]; x1 += ks[1];
  const int R[2][4] = {{13,15,26,6},{17,29,16,24}};
  #pragma unroll
  for (int i = 0; i < 5; i++) {
    #pragma unroll
    for (int j = 0; j < 4; j++) {
      x0 += x1;
      int r = R[i & 1][j];
      x1 = (x1 << r) | (x1 >> (32 - r));
      x1 ^= x0;
    }
    x0 += ks[(i + 1) % 3];
    x1 += ks[(i + 2) % 3] + (uint32_t)(i + 1);
  }
  o0 = x0; o1 = x1;
}

// ---------------------------------------------------------------------------
// THE single IoU implementation. noinline => exactly one compiled copy is
// shared by every caller => bit-identical results across kernels regardless
// of per-kernel contraction/scheduling. contract(off) inside so even an
// inlined/cloned copy would evaluate in strict source order.
// Matches reference: inter / (a_area + g_area - inter), areas (d+1) products.
__device__ __attribute__((noinline))
float iou_pair(float ax1, float ay1, float ax2, float ay2,
               float gx1, float gy1, float gx2, float gy2) {
#pragma clang fp contract(off)
  float aarea = (ax2 - ax1 + 1.f) * (ay2 - ay1 + 1.f);
  float garea = (gx2 - gx1 + 1.f) * (gy2 - gy1 + 1.f);
  float ix = fmaxf(fminf(ax2, gx2) - fmaxf(ax1, gx1) + 1.f, 0.f);
  float iy = fmaxf(fminf(ay2, gy2) - fmaxf(ay1, gy1) + 1.f, 0.f);
  float inter = ix * iy;
  return inter / (aarea + garea - inter);
}

// ---------------------------------------------------------------------------
// K0: per-batch threefry keys only (single tiny block).
__global__ __launch_bounds__(64) void k_init(uint32_t* __restrict__ keys) {
  int i = threadIdx.x;
  if (i < B_) {
    uint32_t k0, k1, kf0, kf1, kb0, kb1;
    tf2x32(0u, 42u, 0u, (uint32_t)i, k0, k1);   // split(root,16)[b]
    tf2x32(k0, k1, 0u, 0u, kf0, kf1);           // kf
    tf2x32(k0, k1, 0u, 1u, kb0, kb1);           // kb
    keys[i * 4 + 0] = kf0;
    keys[i * 4 + 1] = kf1;
    keys[i * 4 + 2] = kb0;
    keys[i * 4 + 3] = kb1;
  }
}

// ---------------------------------------------------------------------------
// K1: gt_max — one block per (b,gt). fmax over {iou of inside anchors} U {0};
// exact-associative; iou bits shared with k_fuse via iou_pair. Direct store.
__global__ __launch_bounds__(256) void k_gtmax(const float* __restrict__ gtb,
                                               const float* __restrict__ iminfo,
                                               float* __restrict__ gt_max) {
  const int b = blockIdx.x / KG_;
  const int g = blockIdx.x % KG_;
  const int tid = threadIdx.x;
  const float* gp = gtb + (b * KG_ + g) * 5;
  const float gx1 = gp[0], gy1 = gp[1], gx2 = gp[2], gy2 = gp[3];
  const float imh = iminfo[0], imw = iminfo[1];
  float best = 0.f;
  for (int loc = tid; loc < HW_; loc += 256) {
    const float sx = 16.f * (float)(loc & 63), sy = 16.f * (float)(loc >> 6);
    #pragma unroll
    for (int a = 0; a < A_; a++) {
      float ax1 = c_base[a][0] + sx, ay1 = c_base[a][1] + sy;
      float ax2 = c_base[a][2] + sx, ay2 = c_base[a][3] + sy;
      bool ins = (ax1 >= 0.f) && (ay1 >= 0.f) && (ax2 < imw) && (ay2 < imh);
      if (ins)
        best = fmaxf(best, iou_pair(ax1, ay1, ax2, ay2, gx1, gy1, gx2, gy2));
    }
  }
  best = fmaxf(best, __shfl_xor(best, 32));
  best = fmaxf(best, __shfl_xor(best, 16));
  best = fmaxf(best, __shfl_xor(best, 8));
  best = fmaxf(best, __shfl_xor(best, 4));
  best = fmaxf(best, __shfl_xor(best, 2));
  best = fmaxf(best, __shfl_xor(best, 1));
  __shared__ float sw[4];
  if ((tid & 63) == 0) sw[tid >> 6] = best;
  __syncthreads();
  if (tid == 0)
    gt_max[b * KG_ + g] = fmaxf(fmaxf(sw[0], sw[1]), fmaxf(sw[2], sw[3]));
}

// ---------------------------------------------------------------------------
// K2: fused labels — ONE 50-IoU loop: max_ovr/argmax/is_best together.
__global__ __launch_bounds__(256) void k_fuse(const float* __restrict__ gtb,
                                              const float* __restrict__ iminfo,
                                              const float* __restrict__ gt_max,
                                              const uint32_t* __restrict__ keys,
                                              float* __restrict__ lbl,
                                              int* __restrict__ amax,
                                              uint32_t* __restrict__ priof,
                                              uint32_t* __restrict__ priob) {
  __shared__ float sgx1[KG_], sgy1[KG_], sgx2[KG_], sgy2[KG_], sgm[KG_];
  const int b = blockIdx.x / NBLK_;
  const int chunk = blockIdx.x % NBLK_;
  const int tid = threadIdx.x;
  if (tid < KG_) {
    const float* g = gtb + (b * KG_ + tid) * 5;
    sgx1[tid] = g[0]; sgy1[tid] = g[1]; sgx2[tid] = g[2]; sgy2[tid] = g[3];
    float gm = gt_max[b * KG_ + tid];
    sgm[tid] = (gm == 0.f) ? 1e-5f : gm;
  }
  __syncthreads();
  const int n = chunk * 256 + tid;
  const int a = n % A_;
  const int loc = n / A_;
  const float sx = 16.f * (float)(loc & 63), sy = 16.f * (float)(loc >> 6);
  const float ax1 = c_base[a][0] + sx, ay1 = c_base[a][1] + sy;
  const float ax2 = c_base[a][2] + sx, ay2 = c_base[a][3] + sy;
  const float imh = iminfo[0], imw = iminfo[1];
  const bool ins = (ax1 >= 0.f) && (ay1 >= 0.f) && (ax2 < imw) && (ay2 < imh);
  float mo = -1.f;
  int bidx = 0;
  bool best = false;
  for (int k = 0; k < KG_; k++) {
    float ovr = iou_pair(ax1, ay1, ax2, ay2,
                         sgx1[k], sgy1[k], sgx2[k], sgy2[k]);
    if (ovr > mo) { mo = ovr; bidx = k; }      // first-argmax (matches jnp)
    best = best || (ovr == sgm[k]);
  }
  float l = -1.f;
  if (ins) {
    if (mo < 0.3f) l = 0.f;
    if (best || mo >= 0.7f) l = 1.f;
  }
  lbl[(size_t)b * N_ + n] = l;
  amax[(size_t)b * N_ + n] = bidx;
  uint32_t y0, y1;
  tf2x32(keys[b * 4 + 0], keys[b * 4 + 1], 0u, (uint32_t)n, y0, y1);
  priof[(size_t)b * N_ + n] = (y0 ^ y1) >> 9;
  tf2x32(keys[b * 4 + 2], keys[b * 4 + 3], 0u, (uint32_t)n, y0, y1);
  priob[(size_t)b * N_ + n] = (y0 ^ y1) >> 9;
}

// ---------------------------------------------------------------------------
// K3 (R3 VERBATIM): per-batch subsample, in-place on lbl.
__global__ __launch_bounds__(256) void k_sub2(float* __restrict__ lbl,
                                              const uint32_t* __restrict__ priof,
                                              const uint32_t* __restrict__ priob,
                                              float* __restrict__ uw) {
  const int b = blockIdx.x;
  const int tid = threadIdx.x;
  __shared__ int sh_hist[256];
  __shared__ int sh_cnt;
  __shared__ int sh_bin, sh_r, s_n;
  __shared__ unsigned long long s_keys[2048];
  __shared__ unsigned long long sh_kstar;

  float* L = lbl + (size_t)b * N_;
  int fg_kept = 0, bg_kept = 0;

  for (int phase = 0; phase < 2; phase++) {
    const float maskv = (phase == 0) ? 1.f : 0.f;
    const int limit = (phase == 0) ? 128 : (256 - fg_kept);
    const uint32_t* P = ((phase == 0) ? priof : priob) + (size_t)b * N_;
    const float4* L4 = (const float4*)L;
    const uint4* P4 = (const uint4*)P;

    // pass 1: count masked
    if (tid == 0) sh_cnt = 0;
    __syncthreads();
    int c0 = 0;
    for (int i4 = tid; i4 < N_ / 4; i4 += 256) {
      float4 v = L4[i4];
      c0 += (v.x == maskv) + (v.y == maskv) + (v.z == maskv) + (v.w == maskv);
    }
    atomicAdd(&sh_cnt, c0);
    __syncthreads();
    const int M = sh_cnt;

    if (M > limit) {
      // pass 2: 256-bin hist of m>>15 over masked elems
      sh_hist[tid] = 0;
      __syncthreads();
      for (int i4 = tid; i4 < N_ / 4; i4 += 256) {
        float4 v = L4[i4];
        uint4 m4 = P4[i4];
        if (v.x == maskv) atomicAdd(&sh_hist[m4.x >> 15], 1);
        if (v.y == maskv) atomicAdd(&sh_hist[m4.y >> 15], 1);
        if (v.z == maskv) atomicAdd(&sh_hist[m4.z >> 15], 1);
        if (v.w == maskv) atomicAdd(&sh_hist[m4.w >> 15], 1);
      }
      __syncthreads();
      // serial bin pick (thread 0): descending bins until cumulative >= limit
      if (tid == 0) {
        int acc = 0, bin = 255;
        for (; bin > 0; bin--) {
          if (acc + sh_hist[bin] >= limit) break;
          acc += sh_hist[bin];
        }
        sh_bin = bin;
        sh_r = limit - acc;   // rank within bin, 1-based, in [1, hist[bin]]
        s_n = 0;
      }
      __syncthreads();
      const int bin0 = sh_bin, r0 = sh_r;
      // pass 3: gather this bin's composite keys
      for (int i4 = tid; i4 < N_ / 4; i4 += 256) {
        float4 v = L4[i4];
        uint4 m4 = P4[i4];
        const float lv[4] = {v.x, v.y, v.z, v.w};
        const uint32_t mv[4] = {m4.x, m4.y, m4.z, m4.w};
        #pragma unroll
        for (int j = 0; j < 4; j++) {
          if (lv[j] == maskv && (int)(mv[j] >> 15) == bin0) {
            int pos = atomicAdd(&s_n, 1);
            if (pos < 2048)
              s_keys[pos] = ((unsigned long long)mv[j] << 16) |
                            (unsigned long long)(65535 - (i4 * 4 + j));
          }
        }
      }
      __syncthreads();
      const int s = min(s_n, 2048);
      // parallel rank: K* = r0-th largest key in bin (keys distinct)
      for (int j = tid; j < s; j += 256) {
        unsigned long long kj = s_keys[j];
        int rank = 0;
        for (int q = 0; q < s; q++) rank += (s_keys[q] > kj) ? 1 : 0;
        if (rank == r0 - 1) sh_kstar = kj;
      }
      __syncthreads();
      const unsigned long long Kst = sh_kstar;
      // pass 4: disable key < K*
      for (int i4 = tid; i4 < N_ / 4; i4 += 256) {
        float4 v = L4[i4];
        uint4 m4 = P4[i4];
        const float lv[4] = {v.x, v.y, v.z, v.w};
        const uint32_t mv[4] = {m4.x, m4.y, m4.z, m4.w};
        #pragma unroll
        for (int j = 0; j < 4; j++) {
          if (lv[j] == maskv) {
            unsigned long long key = ((unsigned long long)mv[j] << 16) |
                                     (unsigned long long)(65535 - (i4 * 4 + j));
            if (key < Kst) L[i4 * 4 + j] = -1.f;
          }
        }
      }
    }
    __syncthreads();
    const int kept = (M <= limit) ? M : limit;
    if (phase == 0) fg_kept = kept; else bg_kept = kept;
    __syncthreads();
  }
  if (tid == 0) uw[b] = 1.f / (float)(fg_kept + bg_kept);
}

// ---------------------------------------------------------------------------
// K4 (R3 VERBATIM): write all outputs in transposed layouts, coalesced in w.
__global__ __launch_bounds__(256) void k_out(const float* __restrict__ gtb,
                                             const float* __restrict__ iminfo,
                                             const float* __restrict__ lbl,
                                             const int* __restrict__ amax,
                                             const float* __restrict__ uw,
                                             float* __restrict__ out) {
  const int t = blockIdx.x * 256 + threadIdx.x;  // 0 .. S0_-1 exactly
  const int w = t & 63;
  const int h = (t >> 6) & 63;
  const int a = (t >> 12) % A_;
  const int b = t / (A_ * HW_);
  const int n = (h * W_ + w) * A_ + a;

  const float ax1 = c_base[a][0] + 16.f * (float)w;
  const float ay1 = c_base[a][1] + 16.f * (float)h;
  const float ax2 = c_base[a][2] + 16.f * (float)w;
  const float ay2 = c_base[a][3] + 16.f * (float)h;
  const float imh = iminfo[0], imw = iminfo[1];
  const bool ins = (ax1 >= 0.f) && (ay1 >= 0.f) && (ax2 < imw) && (ay2 < imh);

  const float l = lbl[(size_t)b * N_ + n];

  // labels: (B,1,A*H,W)
  out[(size_t)b * (A_ * HW_) + a * HW_ + h * W_ + w] = ins ? l : 0.f;

  // targets
  float tx = 0.f, ty = 0.f, tw = 0.f, th = 0.f;
  if (ins) {
    const int g = amax[(size_t)b * N_ + n];
    const float* gp = gtb + ((size_t)b * KG_ + g) * 5;
    float aw = ax2 - ax1 + 1.f, ah = ay2 - ay1 + 1.f;
    float acx = ax1 + 0.5f * (aw - 1.f), acy = ay1 + 0.5f * (ah - 1.f);
    float gw = gp[2] - gp[0] + 1.f, gh = gp[3] - gp[1] + 1.f;
    float gcx = gp[0] + 0.5f * (gw - 1.f), gcy = gp[1] + 0.5f * (gh - 1.f);
    tx = (gcx - acx) / aw;
    ty = (gcy - acy) / ah;
    tw = logf(gw / aw);
    th = logf(gh / ah);
  }
  float* o1 = out + S0_;
  const size_t toff = (size_t)b * (4 * A_ * HW_) + (4 * a) * HW_ + h * W_ + w;
  o1[toff]           = tx;
  o1[toff + HW_]     = ty;
  o1[toff + 2 * HW_] = tw;
  o1[toff + 3 * HW_] = th;

  const float inw = (ins && l == 1.f) ? 1.f : 0.f;
  const float oww = (ins && (l == 0.f || l == 1.f)) ? uw[b] : 0.f;
  float* o2 = out + S0_ + S1_;
  o2[toff] = inw; o2[toff + HW_] = inw; o2[toff + 2 * HW_] = inw; o2[toff + 3 * HW_] = inw;
  float* o3 = out + S0_ + 2 * (size_t)S1_;
  o3[toff] = oww; o3[toff + HW_] = oww; o3[toff + 2 * HW_] = oww; o3[toff + 3 * HW_] = oww;
}

// ---------------------------------------------------------------------------
extern "C" void kernel_launch(void* const* d_in, const int* in_sizes, int n_in,
                              void* d_out, int out_size, void* d_ws, size_t ws_size,
                              hipStream_t stream) {
  const float* gtb = (const float*)d_in[1];     // gt_boxes (B,50,5)
  const float* iminfo = (const float*)d_in[2];  // im_info  (B,2)
  float* out = (float*)d_out;

  // workspace layout (~9.5 MB)
  float* lbl = (float*)d_ws;                       // B*N
  int* amax = (int*)(lbl + (size_t)B_ * N_);       // B*N
  float* gt_max = (float*)(amax + (size_t)B_ * N_);// B*KG
  float* uw = gt_max + B_ * KG_;                   // B
  uint32_t* keys = (uint32_t*)(uw + B_);           // B*4
  uint32_t* priof = keys + B_ * 4;                 // B*N (16B-aligned)
  uint32_t* priob = priof + (size_t)B_ * N_;       // B*N

  k_init<<<1, 64, 0, stream>>>(keys);
  k_gtmax<<<B_ * KG_, 256, 0, stream>>>(gtb, iminfo, gt_max);
  k_fuse<<<B_ * NBLK_, 256, 0, stream>>>(gtb, iminfo, gt_max, keys,
                                         lbl, amax, priof, priob);
  k_sub2<<<B_, 256, 0, stream>>>(lbl, priof, priob, uw);
  k_out<<<S0_ / 256, 256, 0, stream>>>(gtb, iminfo, lbl, amax, uw, out);
}

// Round 7
// 194.261 us; speedup vs baseline: 2.4264x; 1.3125x over previous
//
#include <hip/hip_runtime.h>
#include <stdint.h>

// ---------------------------------------------------------------------------
// RPN anchor-target layer for MI355X — round 7.
//
// Verified invariants:
//  * iou_pair is ONE noinline compiled copy shared by k_gtmax and k_fuse =>
//    bit-identical IoU across kernels (is_best float-equality). DO NOT inline.
//  * JAX partitionable threefry; composite key (m<<16)|(65535-n), distinct.
//
// Changes vs R6 (pass, 255 us):
//  * k_sub3: 1024-thread fused 3-pass subsample (replaces 8-pass k_sub2);
//    logic is a pure pass-fusion of the R3/R6-verified selection math.
//  * k_init folded into k_gtmax block 0 (one fewer launch).
// ---------------------------------------------------------------------------

#define B_   16
#define A_   9
#define H_   64
#define W_   64
#define HW_  (H_*W_)
#define N_   (HW_*A_)      // 36864
#define KG_  50
#define NBLK_ (N_/256)     // 144 blocks per batch image
#define S0_  (B_*A_*HW_)   // labels elems
#define S1_  (B_*4*A_*HW_) // targets / in_w / out_w elems

typedef unsigned long long ull;

// base anchors from generate_anchors() (exact: all half-integers cancel)
__constant__ float c_base[A_][4] = {
  { -84.f,  -40.f,  99.f,  55.f},
  {-176.f,  -88.f, 191.f, 103.f},
  {-360.f, -184.f, 375.f, 199.f},
  { -56.f,  -56.f,  71.f,  71.f},
  {-120.f, -120.f, 135.f, 135.f},
  {-248.f, -248.f, 263.f, 263.f},
  { -36.f,  -80.f,  51.f,  95.f},
  { -80.f, -168.f,  95.f, 183.f},
  {-168.f, -344.f, 183.f, 359.f},
};

__device__ __forceinline__ void tf2x32(uint32_t k0, uint32_t k1,
                                       uint32_t x0, uint32_t x1,
                                       uint32_t& o0, uint32_t& o1) {
  const uint32_t ks2 = k0 ^ k1 ^ 0x1BD11BDAu;
  uint32_t ks[3] = {k0, k1, ks2};
  x0 += ks[0]; x1 += ks[1];
  const int R[2][4] = {{13,15,26,6},{17,29,16,24}};
  #pragma unroll
  for (int i = 0; i < 5; i++) {
    #pragma unroll
    for (int j = 0; j < 4; j++) {
      x0 += x1;
      int r = R[i & 1][j];
      x1 = (x1 << r) | (x1 >> (32 - r));
      x1 ^= x0;
    }
    x0 += ks[(i + 1) % 3];
    x1 += ks[(i + 2) % 3] + (uint32_t)(i + 1);
  }
  o0 = x0; o1 = x1;
}

// ---------------------------------------------------------------------------
// THE single IoU implementation. noinline => exactly one compiled copy shared
// by every caller => bit-identical results across kernels regardless of
// per-kernel contraction/scheduling. contract(off) inside as belt-and-braces.
__device__ __attribute__((noinline))
float iou_pair(float ax1, float ay1, float ax2, float ay2,
               float gx1, float gy1, float gx2, float gy2) {
#pragma clang fp contract(off)
  float aarea = (ax2 - ax1 + 1.f) * (ay2 - ay1 + 1.f);
  float garea = (gx2 - gx1 + 1.f) * (gy2 - gy1 + 1.f);
  float ix = fmaxf(fminf(ax2, gx2) - fmaxf(ax1, gx1) + 1.f, 0.f);
  float iy = fmaxf(fminf(ay2, gy2) - fmaxf(ay1, gy1) + 1.f, 0.f);
  float inter = ix * iy;
  return inter / (aarea + garea - inter);
}

// ---------------------------------------------------------------------------
// K1: gt_max — one block per (b,gt); block 0 also derives threefry keys.
__global__ __launch_bounds__(256) void k_gtmax(const float* __restrict__ gtb,
                                               const float* __restrict__ iminfo,
                                               float* __restrict__ gt_max,
                                               uint32_t* __restrict__ keys) {
  const int b = blockIdx.x / KG_;
  const int g = blockIdx.x % KG_;
  const int tid = threadIdx.x;
  if (blockIdx.x == 0 && tid < B_) {
    uint32_t k0, k1, kf0, kf1, kb0, kb1;
    tf2x32(0u, 42u, 0u, (uint32_t)tid, k0, k1);  // split(root,16)[b]
    tf2x32(k0, k1, 0u, 0u, kf0, kf1);            // kf
    tf2x32(k0, k1, 0u, 1u, kb0, kb1);            // kb
    keys[tid * 4 + 0] = kf0;
    keys[tid * 4 + 1] = kf1;
    keys[tid * 4 + 2] = kb0;
    keys[tid * 4 + 3] = kb1;
  }
  const float* gp = gtb + (b * KG_ + g) * 5;
  const float gx1 = gp[0], gy1 = gp[1], gx2 = gp[2], gy2 = gp[3];
  const float imh = iminfo[0], imw = iminfo[1];
  float best = 0.f;
  for (int loc = tid; loc < HW_; loc += 256) {
    const float sx = 16.f * (float)(loc & 63), sy = 16.f * (float)(loc >> 6);
    #pragma unroll
    for (int a = 0; a < A_; a++) {
      float ax1 = c_base[a][0] + sx, ay1 = c_base[a][1] + sy;
      float ax2 = c_base[a][2] + sx, ay2 = c_base[a][3] + sy;
      bool ins = (ax1 >= 0.f) && (ay1 >= 0.f) && (ax2 < imw) && (ay2 < imh);
      if (ins)
        best = fmaxf(best, iou_pair(ax1, ay1, ax2, ay2, gx1, gy1, gx2, gy2));
    }
  }
  best = fmaxf(best, __shfl_xor(best, 32));
  best = fmaxf(best, __shfl_xor(best, 16));
  best = fmaxf(best, __shfl_xor(best, 8));
  best = fmaxf(best, __shfl_xor(best, 4));
  best = fmaxf(best, __shfl_xor(best, 2));
  best = fmaxf(best, __shfl_xor(best, 1));
  __shared__ float sw[4];
  if ((tid & 63) == 0) sw[tid >> 6] = best;
  __syncthreads();
  if (tid == 0)
    gt_max[b * KG_ + g] = fmaxf(fmaxf(sw[0], sw[1]), fmaxf(sw[2], sw[3]));
}

// ---------------------------------------------------------------------------
// K2 (R6 verbatim): fused labels — ONE 50-IoU loop.
__global__ __launch_bounds__(256) void k_fuse(const float* __restrict__ gtb,
                                              const float* __restrict__ iminfo,
                                              const float* __restrict__ gt_max,
                                              const uint32_t* __restrict__ keys,
                                              float* __restrict__ lbl,
                                              int* __restrict__ amax,
                                              uint32_t* __restrict__ priof,
                                              uint32_t* __restrict__ priob) {
  __shared__ float sgx1[KG_], sgy1[KG_], sgx2[KG_], sgy2[KG_], sgm[KG_];
  const int b = blockIdx.x / NBLK_;
  const int chunk = blockIdx.x % NBLK_;
  const int tid = threadIdx.x;
  if (tid < KG_) {
    const float* g = gtb + (b * KG_ + tid) * 5;
    sgx1[tid] = g[0]; sgy1[tid] = g[1]; sgx2[tid] = g[2]; sgy2[tid] = g[3];
    float gm = gt_max[b * KG_ + tid];
    sgm[tid] = (gm == 0.f) ? 1e-5f : gm;
  }
  __syncthreads();
  const int n = chunk * 256 + tid;
  const int a = n % A_;
  const int loc = n / A_;
  const float sx = 16.f * (float)(loc & 63), sy = 16.f * (float)(loc >> 6);
  const float ax1 = c_base[a][0] + sx, ay1 = c_base[a][1] + sy;
  const float ax2 = c_base[a][2] + sx, ay2 = c_base[a][3] + sy;
  const float imh = iminfo[0], imw = iminfo[1];
  const bool ins = (ax1 >= 0.f) && (ay1 >= 0.f) && (ax2 < imw) && (ay2 < imh);
  float mo = -1.f;
  int bidx = 0;
  bool best = false;
  for (int k = 0; k < KG_; k++) {
    float ovr = iou_pair(ax1, ay1, ax2, ay2,
                         sgx1[k], sgy1[k], sgx2[k], sgy2[k]);
    if (ovr > mo) { mo = ovr; bidx = k; }      // first-argmax (matches jnp)
    best = best || (ovr == sgm[k]);
  }
  float l = -1.f;
  if (ins) {
    if (mo < 0.3f) l = 0.f;
    if (best || mo >= 0.7f) l = 1.f;
  }
  lbl[(size_t)b * N_ + n] = l;
  amax[(size_t)b * N_ + n] = bidx;
  uint32_t y0, y1;
  tf2x32(keys[b * 4 + 0], keys[b * 4 + 1], 0u, (uint32_t)n, y0, y1);
  priof[(size_t)b * N_ + n] = (y0 ^ y1) >> 9;
  tf2x32(keys[b * 4 + 2], keys[b * 4 + 3], 0u, (uint32_t)n, y0, y1);
  priob[(size_t)b * N_ + n] = (y0 ^ y1) >> 9;
}

// ---------------------------------------------------------------------------
// K3: fused subsample, 1024 threads. Pass A: joint fg/bg hist; serial bin
// pick (both phases); pass B: joint gather + in-LDS rank -> K*; pass C:
// joint disable.  Pure pass-fusion of the R3/R6-verified selection math.
__global__ __launch_bounds__(1024) void k_sub3(float* __restrict__ lbl,
                                               const uint32_t* __restrict__ priof,
                                               const uint32_t* __restrict__ priob,
                                               float* __restrict__ uw) {
  const int b = blockIdx.x;
  const int tid = threadIdx.x;
  __shared__ int hf[256], hb[256];
  __shared__ int s_binF, s_rF, s_binB, s_rB, s_needF, s_needB, s_nf, s_nb;
  __shared__ float s_uw;
  __shared__ ull kF[2048], kB[2048];
  __shared__ ull s_KF, s_KB;

  float* L = lbl + (size_t)b * N_;
  const float4* L4 = (const float4*)L;
  const uint4* Pf4 = (const uint4*)(priof + (size_t)b * N_);
  const uint4* Pb4 = (const uint4*)(priob + (size_t)b * N_);

  if (tid < 256) { hf[tid] = 0; hb[tid] = 0; }
  if (tid == 0) { s_nf = 0; s_nb = 0; }
  __syncthreads();

  // pass A: joint histogram of m>>15 per phase
  for (int i4 = tid; i4 < N_ / 4; i4 += 1024) {
    float4 v = L4[i4];
    uint4 mf = Pf4[i4];
    uint4 mb = Pb4[i4];
    const float lv[4] = {v.x, v.y, v.z, v.w};
    const uint32_t fv[4] = {mf.x, mf.y, mf.z, mf.w};
    const uint32_t bv[4] = {mb.x, mb.y, mb.z, mb.w};
    #pragma unroll
    for (int j = 0; j < 4; j++) {
      if (lv[j] == 1.f) atomicAdd(&hf[fv[j] >> 15], 1);
      else if (lv[j] == 0.f) atomicAdd(&hb[bv[j] >> 15], 1);
    }
  }
  __syncthreads();

  if (tid == 0) {
    int acc = 0, binF = -1, rF = 0;
    for (int bin = 255; bin >= 0; bin--) {
      int hv = hf[bin];
      if (binF < 0 && acc + hv >= 128) { binF = bin; rF = 128 - acc; }
      acc += hv;
    }
    const int Mf = acc;
    const int kf = (Mf < 128) ? Mf : 128;
    const int limB = 256 - kf;
    int accb = 0, binB = -1, rB = 0;
    for (int bin = 255; bin >= 0; bin--) {
      int hv = hb[bin];
      if (binB < 0 && accb + hv >= limB) { binB = bin; rB = limB - accb; }
      accb += hv;
    }
    const int Mb = accb;
    const int kb = (Mb < limB) ? Mb : limB;
    s_needF = (Mf > 128);
    s_binF = binF; s_rF = rF;
    s_needB = (Mb > limB);
    s_binB = binB; s_rB = rB;
    s_uw = 1.f / (float)(kf + kb);
  }
  __syncthreads();
  const int needF = s_needF, needB = s_needB;
  const int binF = s_binF, binB = s_binB;

  if (needF || needB) {
    // pass B: gather cutoff-bin keys for both phases
    for (int i4 = tid; i4 < N_ / 4; i4 += 1024) {
      float4 v = L4[i4];
      uint4 mf = Pf4[i4];
      uint4 mb = Pb4[i4];
      const float lv[4] = {v.x, v.y, v.z, v.w};
      const uint32_t fv[4] = {mf.x, mf.y, mf.z, mf.w};
      const uint32_t bv[4] = {mb.x, mb.y, mb.z, mb.w};
      #pragma unroll
      for (int j = 0; j < 4; j++) {
        if (needF && lv[j] == 1.f && (int)(fv[j] >> 15) == binF) {
          int p = atomicAdd(&s_nf, 1);
          if (p < 2048)
            kF[p] = ((ull)fv[j] << 16) | (ull)(65535 - (i4 * 4 + j));
        }
        if (needB && lv[j] == 0.f && (int)(bv[j] >> 15) == binB) {
          int p = atomicAdd(&s_nb, 1);
          if (p < 2048)
            kB[p] = ((ull)bv[j] << 16) | (ull)(65535 - (i4 * 4 + j));
        }
      }
    }
    __syncthreads();
    const int sf = min(s_nf, 2048), sb = min(s_nb, 2048);
    if (needF) {
      for (int j = tid; j < sf; j += 1024) {
        ull kj = kF[j];
        int rank = 0;
        for (int q = 0; q < sf; q++) rank += (kF[q] > kj) ? 1 : 0;
        if (rank == s_rF - 1) s_KF = kj;   // unique writer (keys distinct)
      }
    }
    if (needB) {
      for (int j = tid; j < sb; j += 1024) {
        ull kj = kB[j];
        int rank = 0;
        for (int q = 0; q < sb; q++) rank += (kB[q] > kj) ? 1 : 0;
        if (rank == s_rB - 1) s_KB = kj;
      }
    }
    __syncthreads();
    const ull KF_ = needF ? s_KF : 0ull;
    const ull KB_ = needB ? s_KB : 0ull;
    // pass C: joint disable (key < K*)
    for (int i4 = tid; i4 < N_ / 4; i4 += 1024) {
      float4 v = L4[i4];
      uint4 mf = Pf4[i4];
      uint4 mb = Pb4[i4];
      const float lv[4] = {v.x, v.y, v.z, v.w};
      const uint32_t fv[4] = {mf.x, mf.y, mf.z, mf.w};
      const uint32_t bv[4] = {mb.x, mb.y, mb.z, mb.w};
      #pragma unroll
      for (int j = 0; j < 4; j++) {
        if (needF && lv[j] == 1.f) {
          ull key = ((ull)fv[j] << 16) | (ull)(65535 - (i4 * 4 + j));
          if (key < KF_) L[i4 * 4 + j] = -1.f;
        } else if (needB && lv[j] == 0.f) {
          ull key = ((ull)bv[j] << 16) | (ull)(65535 - (i4 * 4 + j));
          if (key < KB_) L[i4 * 4 + j] = -1.f;
        }
      }
    }
  }
  if (tid == 0) uw[b] = s_uw;
}

// ---------------------------------------------------------------------------
// K4 (R6 verbatim): write all outputs in transposed layouts, coalesced in w.
__global__ __launch_bounds__(256) void k_out(const float* __restrict__ gtb,
                                             const float* __restrict__ iminfo,
                                             const float* __restrict__ lbl,
                                             const int* __restrict__ amax,
                                             const float* __restrict__ uw,
                                             float* __restrict__ out) {
  const int t = blockIdx.x * 256 + threadIdx.x;  // 0 .. S0_-1 exactly
  const int w = t & 63;
  const int h = (t >> 6) & 63;
  const int a = (t >> 12) % A_;
  const int b = t / (A_ * HW_);
  const int n = (h * W_ + w) * A_ + a;

  const float ax1 = c_base[a][0] + 16.f * (float)w;
  const float ay1 = c_base[a][1] + 16.f * (float)h;
  const float ax2 = c_base[a][2] + 16.f * (float)w;
  const float ay2 = c_base[a][3] + 16.f * (float)h;
  const float imh = iminfo[0], imw = iminfo[1];
  const bool ins = (ax1 >= 0.f) && (ay1 >= 0.f) && (ax2 < imw) && (ay2 < imh);

  const float l = lbl[(size_t)b * N_ + n];

  // labels: (B,1,A*H,W)
  out[(size_t)b * (A_ * HW_) + a * HW_ + h * W_ + w] = ins ? l : 0.f;

  // targets
  float tx = 0.f, ty = 0.f, tw = 0.f, th = 0.f;
  if (ins) {
    const int g = amax[(size_t)b * N_ + n];
    const float* gp = gtb + ((size_t)b * KG_ + g) * 5;
    float aw = ax2 - ax1 + 1.f, ah = ay2 - ay1 + 1.f;
    float acx = ax1 + 0.5f * (aw - 1.f), acy = ay1 + 0.5f * (ah - 1.f);
    float gw = gp[2] - gp[0] + 1.f, gh = gp[3] - gp[1] + 1.f;
    float gcx = gp[0] + 0.5f * (gw - 1.f), gcy = gp[1] + 0.5f * (gh - 1.f);
    tx = (gcx - acx) / aw;
    ty = (gcy - acy) / ah;
    tw = logf(gw / aw);
    th = logf(gh / ah);
  }
  float* o1 = out + S0_;
  const size_t toff = (size_t)b * (4 * A_ * HW_) + (4 * a) * HW_ + h * W_ + w;
  o1[toff]           = tx;
  o1[toff + HW_]     = ty;
  o1[toff + 2 * HW_] = tw;
  o1[toff + 3 * HW_] = th;

  const float inw = (ins && l == 1.f) ? 1.f : 0.f;
  const float oww = (ins && (l == 0.f || l == 1.f)) ? uw[b] : 0.f;
  float* o2 = out + S0_ + S1_;
  o2[toff] = inw; o2[toff + HW_] = inw; o2[toff + 2 * HW_] = inw; o2[toff + 3 * HW_] = inw;
  float* o3 = out + S0_ + 2 * (size_t)S1_;
  o3[toff] = oww; o3[toff + HW_] = oww; o3[toff + 2 * HW_] = oww; o3[toff + 3 * HW_] = oww;
}

// ---------------------------------------------------------------------------
extern "C" void kernel_launch(void* const* d_in, const int* in_sizes, int n_in,
                              void* d_out, int out_size, void* d_ws, size_t ws_size,
                              hipStream_t stream) {
  const float* gtb = (const float*)d_in[1];     // gt_boxes (B,50,5)
  const float* iminfo = (const float*)d_in[2];  // im_info  (B,2)
  float* out = (float*)d_out;

  // workspace layout (~9.5 MB)
  float* lbl = (float*)d_ws;                       // B*N
  int* amax = (int*)(lbl + (size_t)B_ * N_);       // B*N
  float* gt_max = (float*)(amax + (size_t)B_ * N_);// B*KG
  float* uw = gt_max + B_ * KG_;                   // B
  uint32_t* keys = (uint32_t*)(uw + B_);           // B*4
  uint32_t* priof = keys + B_ * 4;                 // B*N (16B-aligned)
  uint32_t* priob = priof + (size_t)B_ * N_;       // B*N

  k_gtmax<<<B_ * KG_, 256, 0, stream>>>(gtb, iminfo, gt_max, keys);
  k_fuse<<<B_ * NBLK_, 256, 0, stream>>>(gtb, iminfo, gt_max, keys,
                                         lbl, amax, priof, priob);
  k_sub3<<<B_, 1024, 0, stream>>>(lbl, priof, priob, uw);
  k_out<<<S0_ / 256, 256, 0, stream>>>(gtb, iminfo, lbl, amax, uw, out);
}

// Round 8
// 156.218 us; speedup vs baseline: 3.0173x; 1.2435x over previous
//
#include <hip/hip_runtime.h>
#include <stdint.h>

// ---------------------------------------------------------------------------
// RPN anchor-target layer for MI355X — round 8.
//
// Verified invariants (R6/R7):
//  * ALL IoU math goes through ONE noinline compiled copy (iou_core +
//    box_area_f) => bit-identical across kernels (is_best float-equality).
//    DO NOT inline, DO NOT duplicate the formula.
//  * iou_core interior op order is the R1-validated sequence (matches jnp).
//  * JAX partitionable threefry; composite key (m<<16)|(65535-n), distinct.
//
// Changes vs R7 (pass, 194 us; k_fuse 46 us @ 91% VALUBusy):
//  * k_fuse iterates ONLY inside anchors (9 runtime rectangles, compacted
//    index space, grid-stride). Non-inside lbl entries = -1 via k_gtmax.
//  * k_gtmax prunes to the overlap-AND-inside rectangle per (gt,a): pruned
//    anchors provably have ovr_in == 0 (exact), contributing nothing to fmax.
//  * areas hoisted out of inner loops (aarea per anchor, garea per gt).
// ---------------------------------------------------------------------------

#define B_   16
#define A_   9
#define H_   64
#define W_   64
#define HW_  (H_*W_)
#define N_   (HW_*A_)      // 36864
#define KG_  50
#define S0_  (B_*A_*HW_)   // labels elems
#define S1_  (B_*4*A_*HW_) // targets / in_w / out_w elems
#define NGTB_ (B_*KG_)     // k_gtmax blocks
#define LCLR_ ((B_*N_ + NGTB_ - 1) / NGTB_)   // lbl floats cleared per block

typedef unsigned long long ull;

// base anchors from generate_anchors() (exact: all half-integers cancel)
__constant__ float c_base[A_][4] = {
  { -84.f,  -40.f,  99.f,  55.f},
  {-176.f,  -88.f, 191.f, 103.f},
  {-360.f, -184.f, 375.f, 199.f},
  { -56.f,  -56.f,  71.f,  71.f},
  {-120.f, -120.f, 135.f, 135.f},
  {-248.f, -248.f, 263.f, 263.f},
  { -36.f,  -80.f,  51.f,  95.f},
  { -80.f, -168.f,  95.f, 183.f},
  {-168.f, -344.f, 183.f, 359.f},
};

__device__ __forceinline__ void tf2x32(uint32_t k0, uint32_t k1,
                                       uint32_t x0, uint32_t x1,
                                       uint32_t& o0, uint32_t& o1) {
  const uint32_t ks2 = k0 ^ k1 ^ 0x1BD11BDAu;
  uint32_t ks[3] = {k0, k1, ks2};
  x0 += ks[0]; x1 += ks[1];
  const int R[2][4] = {{13,15,26,6},{17,29,16,24}};
  #pragma unroll
  for (int i = 0; i < 5; i++) {
    #pragma unroll
    for (int j = 0; j < 4; j++) {
      x0 += x1;
      int r = R[i & 1][j];
      x1 = (x1 << r) | (x1 >> (32 - r));
      x1 ^= x0;
    }
    x0 += ks[(i + 1) % 3];
    x1 += ks[(i + 2) % 3] + (uint32_t)(i + 1);
  }
  o0 = x0; o1 = x1;
}

// ---------------------------------------------------------------------------
// Shared noinline numerics: single compiled copy each => cross-kernel
// bit-identity by construction. contract(off) as belt-and-braces.
__device__ __attribute__((noinline))
float box_area_f(float x1, float y1, float x2, float y2) {
#pragma clang fp contract(off)
  return (x2 - x1 + 1.f) * (y2 - y1 + 1.f);
}

__device__ __attribute__((noinline))
float iou_core(float ax1, float ay1, float ax2, float ay2, float aarea,
               float gx1, float gy1, float gx2, float gy2, float garea) {
#pragma clang fp contract(off)
  float ix = fmaxf(fminf(ax2, gx2) - fmaxf(ax1, gx1) + 1.f, 0.f);
  float iy = fmaxf(fminf(ay2, gy2) - fmaxf(ay1, gy1) + 1.f, 0.f);
  float inter = ix * iy;
  return inter / (aarea + garea - inter);
}

// ---------------------------------------------------------------------------
// K1: gt_max — one block per (b,gt), pruned to overlap∩inside rectangle per
// anchor type. Also: block 0 derives threefry keys; every block clears its
// slice of lbl to -1 (non-inside anchors are never touched by k_fuse).
__global__ __launch_bounds__(256) void k_gtmax(const float* __restrict__ gtb,
                                               const float* __restrict__ iminfo,
                                               float* __restrict__ gt_max,
                                               uint32_t* __restrict__ keys,
                                               float* __restrict__ lbl) {
  const int b = blockIdx.x / KG_;
  const int g = blockIdx.x % KG_;
  const int tid = threadIdx.x;
  if (blockIdx.x == 0 && tid < B_) {
    uint32_t k0, k1, kf0, kf1, kb0, kb1;
    tf2x32(0u, 42u, 0u, (uint32_t)tid, k0, k1);  // split(root,16)[b]
    tf2x32(k0, k1, 0u, 0u, kf0, kf1);            // kf
    tf2x32(k0, k1, 0u, 1u, kb0, kb1);            // kb
    keys[tid * 4 + 0] = kf0;
    keys[tid * 4 + 1] = kf1;
    keys[tid * 4 + 2] = kb0;
    keys[tid * 4 + 3] = kb1;
  }
  {  // clear this block's lbl slice to -1
    const int base = blockIdx.x * LCLR_;
    const int lim = min(base + LCLR_, B_ * N_);
    for (int i = base + tid; i < lim; i += 256) lbl[i] = -1.f;
  }
  const float* gp = gtb + (b * KG_ + g) * 5;
  const float gx1 = gp[0], gy1 = gp[1], gx2 = gp[2], gy2 = gp[3];
  const float garea = box_area_f(gx1, gy1, gx2, gy2);
  const float imh = iminfo[0], imw = iminfo[1];
  float best = 0.f;
  for (int a = 0; a < A_; a++) {
    const float bx1 = c_base[a][0], by1 = c_base[a][1];
    const float bx2 = c_base[a][2], by2 = c_base[a][3];
    const float aarea = box_area_f(bx1, by1, bx2, by2);  // == shifted (exact ints)
    // inside rectangle (exact: coords are exact integers, /16 exact)
    int xlo = max(0, (int)ceilf(-bx1 / 16.f));
    int xhi = min(W_ - 1, (int)ceilf((imw - bx2) / 16.f) - 1);
    int ylo = max(0, (int)ceilf(-by1 / 16.f));
    int yhi = min(H_ - 1, (int)ceilf((imh - by2) / 16.f) - 1);
    // overlap pruning (conservative +-1 loc; pruned anchors have ix or iy == 0)
    xlo = max(xlo, (int)floorf((gx1 - 1.f - bx2) / 16.f));
    xhi = min(xhi, (int)ceilf((gx2 + 1.f - bx1) / 16.f));
    ylo = max(ylo, (int)floorf((gy1 - 1.f - by2) / 16.f));
    yhi = min(yhi, (int)ceilf((gy2 + 1.f - by1) / 16.f));
    const int nx = xhi - xlo + 1, ny = yhi - ylo + 1;
    if (nx <= 0 || ny <= 0) continue;
    const int lw = (nx <= 1) ? 0 : (32 - __clz(nx - 1));  // 2^lw >= nx
    const int tot = ny << lw;
    const int mask = (1 << lw) - 1;
    for (int t = tid; t < tot; t += 256) {
      const int xi = t & mask;
      if (xi >= nx) continue;
      const int x = xlo + xi;
      const int y = ylo + (t >> lw);
      const float sx = 16.f * (float)x, sy = 16.f * (float)y;
      best = fmaxf(best, iou_core(bx1 + sx, by1 + sy, bx2 + sx, by2 + sy,
                                  aarea, gx1, gy1, gx2, gy2, garea));
    }
  }
  best = fmaxf(best, __shfl_xor(best, 32));
  best = fmaxf(best, __shfl_xor(best, 16));
  best = fmaxf(best, __shfl_xor(best, 8));
  best = fmaxf(best, __shfl_xor(best, 4));
  best = fmaxf(best, __shfl_xor(best, 2));
  best = fmaxf(best, __shfl_xor(best, 1));
  __shared__ float sw[4];
  if ((tid & 63) == 0) sw[tid >> 6] = best;
  __syncthreads();
  if (tid == 0)
    gt_max[b * KG_ + g] = fmaxf(fmaxf(sw[0], sw[1]), fmaxf(sw[2], sw[3]));
}

// ---------------------------------------------------------------------------
// K2: fused labels over the COMPACTED inside-anchor index space.
// grid = (73, B_); grid-stride over C = sum of 9 inside-rectangle sizes.
__global__ __launch_bounds__(256) void k_fuse(const float* __restrict__ gtb,
                                              const float* __restrict__ iminfo,
                                              const float* __restrict__ gt_max,
                                              const uint32_t* __restrict__ keys,
                                              float* __restrict__ lbl,
                                              int* __restrict__ amax,
                                              uint32_t* __restrict__ priof,
                                              uint32_t* __restrict__ priob) {
  __shared__ float sgx1[KG_], sgy1[KG_], sgx2[KG_], sgy2[KG_], sga[KG_], sgm[KG_];
  __shared__ int s_xlo[A_], s_ylo[A_], s_nx[A_], s_pre[A_ + 1];
  __shared__ uint32_t s_k[4];
  const int b = blockIdx.y;
  const int tid = threadIdx.x;
  if (tid < KG_) {
    const float* g = gtb + (b * KG_ + tid) * 5;
    float x1 = g[0], y1 = g[1], x2 = g[2], y2 = g[3];
    sgx1[tid] = x1; sgy1[tid] = y1; sgx2[tid] = x2; sgy2[tid] = y2;
    sga[tid] = box_area_f(x1, y1, x2, y2);
    float gm = gt_max[b * KG_ + tid];
    sgm[tid] = (gm == 0.f) ? 1e-5f : gm;
  }
  if (tid < 4) s_k[tid] = keys[b * 4 + tid];
  if (tid < A_) {
    const float imh = iminfo[0], imw = iminfo[1];
    const float bx1 = c_base[tid][0], by1 = c_base[tid][1];
    const float bx2 = c_base[tid][2], by2 = c_base[tid][3];
    int xlo = max(0, (int)ceilf(-bx1 / 16.f));
    int xhi = min(W_ - 1, (int)ceilf((imw - bx2) / 16.f) - 1);
    int ylo = max(0, (int)ceilf(-by1 / 16.f));
    int yhi = min(H_ - 1, (int)ceilf((imh - by2) / 16.f) - 1);
    int nx = max(0, xhi - xlo + 1), ny = max(0, yhi - ylo + 1);
    s_xlo[tid] = xlo; s_ylo[tid] = ylo; s_nx[tid] = nx;
    s_pre[tid + 1] = nx * ny;
  }
  __syncthreads();
  if (tid == 0) {
    s_pre[0] = 0;
    for (int a = 0; a < A_; a++) s_pre[a + 1] += s_pre[a];
  }
  __syncthreads();
  const int C = s_pre[A_];

  for (int t = blockIdx.x * 256 + tid; t < C; t += gridDim.x * 256) {
    int a = 0;
    while (t >= s_pre[a + 1]) a++;
    const int idx = t - s_pre[a];
    const int nx = s_nx[a];
    const int y = s_ylo[a] + idx / nx;
    const int x = s_xlo[a] + (idx - (idx / nx) * nx);
    const int n = (y * W_ + x) * A_ + a;
    const float sx = 16.f * (float)x, sy = 16.f * (float)y;
    const float ax1 = c_base[a][0] + sx, ay1 = c_base[a][1] + sy;
    const float ax2 = c_base[a][2] + sx, ay2 = c_base[a][3] + sy;
    const float aarea = box_area_f(c_base[a][0], c_base[a][1],
                                   c_base[a][2], c_base[a][3]);  // == shifted
    float mo = -1.f;
    int bidx = 0;
    bool best = false;
    for (int k = 0; k < KG_; k++) {
      float ovr = iou_core(ax1, ay1, ax2, ay2, aarea,
                           sgx1[k], sgy1[k], sgx2[k], sgy2[k], sga[k]);
      if (ovr > mo) { mo = ovr; bidx = k; }    // first-argmax (matches jnp)
      best = best || (ovr == sgm[k]);
    }
    float l = -1.f;
    if (mo < 0.3f) l = 0.f;
    if (best || mo >= 0.7f) l = 1.f;
    lbl[(size_t)b * N_ + n] = l;
    amax[(size_t)b * N_ + n] = bidx;
    uint32_t y0, y1;
    tf2x32(s_k[0], s_k[1], 0u, (uint32_t)n, y0, y1);
    priof[(size_t)b * N_ + n] = (y0 ^ y1) >> 9;
    tf2x32(s_k[2], s_k[3], 0u, (uint32_t)n, y0, y1);
    priob[(size_t)b * N_ + n] = (y0 ^ y1) >> 9;
  }
}

// ---------------------------------------------------------------------------
// K3 (R7 verbatim): fused subsample, 1024 threads, 3 joint passes.
__global__ __launch_bounds__(1024) void k_sub3(float* __restrict__ lbl,
                                               const uint32_t* __restrict__ priof,
                                               const uint32_t* __restrict__ priob,
                                               float* __restrict__ uw) {
  const int b = blockIdx.x;
  const int tid = threadIdx.x;
  __shared__ int hf[256], hb[256];
  __shared__ int s_binF, s_rF, s_binB, s_rB, s_needF, s_needB, s_nf, s_nb;
  __shared__ float s_uw;
  __shared__ ull kF[2048], kB[2048];
  __shared__ ull s_KF, s_KB;

  float* L = lbl + (size_t)b * N_;
  const float4* L4 = (const float4*)L;
  const uint4* Pf4 = (const uint4*)(priof + (size_t)b * N_);
  const uint4* Pb4 = (const uint4*)(priob + (size_t)b * N_);

  if (tid < 256) { hf[tid] = 0; hb[tid] = 0; }
  if (tid == 0) { s_nf = 0; s_nb = 0; }
  __syncthreads();

  // pass A: joint histogram of m>>15 per phase
  for (int i4 = tid; i4 < N_ / 4; i4 += 1024) {
    float4 v = L4[i4];
    uint4 mf = Pf4[i4];
    uint4 mb = Pb4[i4];
    const float lv[4] = {v.x, v.y, v.z, v.w};
    const uint32_t fv[4] = {mf.x, mf.y, mf.z, mf.w};
    const uint32_t bv[4] = {mb.x, mb.y, mb.z, mb.w};
    #pragma unroll
    for (int j = 0; j < 4; j++) {
      if (lv[j] == 1.f) atomicAdd(&hf[fv[j] >> 15], 1);
      else if (lv[j] == 0.f) atomicAdd(&hb[bv[j] >> 15], 1);
    }
  }
  __syncthreads();

  if (tid == 0) {
    int acc = 0, binF = -1, rF = 0;
    for (int bin = 255; bin >= 0; bin--) {
      int hv = hf[bin];
      if (binF < 0 && acc + hv >= 128) { binF = bin; rF = 128 - acc; }
      acc += hv;
    }
    const int Mf = acc;
    const int kf = (Mf < 128) ? Mf : 128;
    const int limB = 256 - kf;
    int accb = 0, binB = -1, rB = 0;
    for (int bin = 255; bin >= 0; bin--) {
      int hv = hb[bin];
      if (binB < 0 && accb + hv >= limB) { binB = bin; rB = limB - accb; }
      accb += hv;
    }
    const int Mb = accb;
    const int kb = (Mb < limB) ? Mb : limB;
    s_needF = (Mf > 128);
    s_binF = binF; s_rF = rF;
    s_needB = (Mb > limB);
    s_binB = binB; s_rB = rB;
    s_uw = 1.f / (float)(kf + kb);
  }
  __syncthreads();
  const int needF = s_needF, needB = s_needB;
  const int binF = s_binF, binB = s_binB;

  if (needF || needB) {
    // pass B: gather cutoff-bin keys for both phases
    for (int i4 = tid; i4 < N_ / 4; i4 += 1024) {
      float4 v = L4[i4];
      uint4 mf = Pf4[i4];
      uint4 mb = Pb4[i4];
      const float lv[4] = {v.x, v.y, v.z, v.w};
      const uint32_t fv[4] = {mf.x, mf.y, mf.z, mf.w};
      const uint32_t bv[4] = {mb.x, mb.y, mb.z, mb.w};
      #pragma unroll
      for (int j = 0; j < 4; j++) {
        if (needF && lv[j] == 1.f && (int)(fv[j] >> 15) == binF) {
          int p = atomicAdd(&s_nf, 1);
          if (p < 2048)
            kF[p] = ((ull)fv[j] << 16) | (ull)(65535 - (i4 * 4 + j));
        }
        if (needB && lv[j] == 0.f && (int)(bv[j] >> 15) == binB) {
          int p = atomicAdd(&s_nb, 1);
          if (p < 2048)
            kB[p] = ((ull)bv[j] << 16) | (ull)(65535 - (i4 * 4 + j));
        }
      }
    }
    __syncthreads();
    const int sf = min(s_nf, 2048), sb = min(s_nb, 2048);
    if (needF) {
      for (int j = tid; j < sf; j += 1024) {
        ull kj = kF[j];
        int rank = 0;
        for (int q = 0; q < sf; q++) rank += (kF[q] > kj) ? 1 : 0;
        if (rank == s_rF - 1) s_KF = kj;   // unique writer (keys distinct)
      }
    }
    if (needB) {
      for (int j = tid; j < sb; j += 1024) {
        ull kj = kB[j];
        int rank = 0;
        for (int q = 0; q < sb; q++) rank += (kB[q] > kj) ? 1 : 0;
        if (rank == s_rB - 1) s_KB = kj;
      }
    }
    __syncthreads();
    const ull KF_ = needF ? s_KF : 0ull;
    const ull KB_ = needB ? s_KB : 0ull;
    // pass C: joint disable (key < K*)
    for (int i4 = tid; i4 < N_ / 4; i4 += 1024) {
      float4 v = L4[i4];
      uint4 mf = Pf4[i4];
      uint4 mb = Pb4[i4];
      const float lv[4] = {v.x, v.y, v.z, v.w};
      const uint32_t fv[4] = {mf.x, mf.y, mf.z, mf.w};
      const uint32_t bv[4] = {mb.x, mb.y, mb.z, mb.w};
      #pragma unroll
      for (int j = 0; j < 4; j++) {
        if (needF && lv[j] == 1.f) {
          ull key = ((ull)fv[j] << 16) | (ull)(65535 - (i4 * 4 + j));
          if (key < KF_) L[i4 * 4 + j] = -1.f;
        } else if (needB && lv[j] == 0.f) {
          ull key = ((ull)bv[j] << 16) | (ull)(65535 - (i4 * 4 + j));
          if (key < KB_) L[i4 * 4 + j] = -1.f;
        }
      }
    }
  }
  if (tid == 0) uw[b] = s_uw;
}

// ---------------------------------------------------------------------------
// K4 (R7 verbatim): write all outputs in transposed layouts, coalesced in w.
__global__ __launch_bounds__(256) void k_out(const float* __restrict__ gtb,
                                             const float* __restrict__ iminfo,
                                             const float* __restrict__ lbl,
                                             const int* __restrict__ amax,
                                             const float* __restrict__ uw,
                                             float* __restrict__ out) {
  const int t = blockIdx.x * 256 + threadIdx.x;  // 0 .. S0_-1 exactly
  const int w = t & 63;
  const int h = (t >> 6) & 63;
  const int a = (t >> 12) % A_;
  const int b = t / (A_ * HW_);
  const int n = (h * W_ + w) * A_ + a;

  const float ax1 = c_base[a][0] + 16.f * (float)w;
  const float ay1 = c_base[a][1] + 16.f * (float)h;
  const float ax2 = c_base[a][2] + 16.f * (float)w;
  const float ay2 = c_base[a][3] + 16.f * (float)h;
  const float imh = iminfo[0], imw = iminfo[1];
  const bool ins = (ax1 >= 0.f) && (ay1 >= 0.f) && (ax2 < imw) && (ay2 < imh);

  const float l = lbl[(size_t)b * N_ + n];

  // labels: (B,1,A*H,W)
  out[(size_t)b * (A_ * HW_) + a * HW_ + h * W_ + w] = ins ? l : 0.f;

  // targets
  float tx = 0.f, ty = 0.f, tw = 0.f, th = 0.f;
  if (ins) {
    const int g = amax[(size_t)b * N_ + n];
    const float* gp = gtb + ((size_t)b * KG_ + g) * 5;
    float aw = ax2 - ax1 + 1.f, ah = ay2 - ay1 + 1.f;
    float acx = ax1 + 0.5f * (aw - 1.f), acy = ay1 + 0.5f * (ah - 1.f);
    float gw = gp[2] - gp[0] + 1.f, gh = gp[3] - gp[1] + 1.f;
    float gcx = gp[0] + 0.5f * (gw - 1.f), gcy = gp[1] + 0.5f * (gh - 1.f);
    tx = (gcx - acx) / aw;
    ty = (gcy - acy) / ah;
    tw = logf(gw / aw);
    th = logf(gh / ah);
  }
  float* o1 = out + S0_;
  const size_t toff = (size_t)b * (4 * A_ * HW_) + (4 * a) * HW_ + h * W_ + w;
  o1[toff]           = tx;
  o1[toff + HW_]     = ty;
  o1[toff + 2 * HW_] = tw;
  o1[toff + 3 * HW_] = th;

  const float inw = (ins && l == 1.f) ? 1.f : 0.f;
  const float oww = (ins && (l == 0.f || l == 1.f)) ? uw[b] : 0.f;
  float* o2 = out + S0_ + S1_;
  o2[toff] = inw; o2[toff + HW_] = inw; o2[toff + 2 * HW_] = inw; o2[toff + 3 * HW_] = inw;
  float* o3 = out + S0_ + 2 * (size_t)S1_;
  o3[toff] = oww; o3[toff + HW_] = oww; o3[toff + 2 * HW_] = oww; o3[toff + 3 * HW_] = oww;
}

// ---------------------------------------------------------------------------
extern "C" void kernel_launch(void* const* d_in, const int* in_sizes, int n_in,
                              void* d_out, int out_size, void* d_ws, size_t ws_size,
                              hipStream_t stream) {
  const float* gtb = (const float*)d_in[1];     // gt_boxes (B,50,5)
  const float* iminfo = (const float*)d_in[2];  // im_info  (B,2)
  float* out = (float*)d_out;

  // workspace layout (~9.5 MB)
  float* lbl = (float*)d_ws;                       // B*N
  int* amax = (int*)(lbl + (size_t)B_ * N_);       // B*N
  float* gt_max = (float*)(amax + (size_t)B_ * N_);// B*KG
  float* uw = gt_max + B_ * KG_;                   // B
  uint32_t* keys = (uint32_t*)(uw + B_);           // B*4
  uint32_t* priof = keys + B_ * 4;                 // B*N (16B-aligned)
  uint32_t* priob = priof + (size_t)B_ * N_;       // B*N

  k_gtmax<<<NGTB_, 256, 0, stream>>>(gtb, iminfo, gt_max, keys, lbl);
  k_fuse<<<dim3(73, B_), 256, 0, stream>>>(gtb, iminfo, gt_max, keys,
                                           lbl, amax, priof, priob);
  k_sub3<<<B_, 1024, 0, stream>>>(lbl, priof, priob, uw);
  k_out<<<S0_ / 256, 256, 0, stream>>>(gtb, iminfo, lbl, amax, uw, out);
}

// Round 9
// 137.147 us; speedup vs baseline: 3.4369x; 1.1391x over previous
//
#include <hip/hip_runtime.h>
#include <stdint.h>

// ---------------------------------------------------------------------------
// RPN anchor-target layer for MI355X — round 9.
//
// Verified invariants (R6-R8):
//  * ALL IoU math via ONE noinline compiled copy (iou_core + box_area_f) =>
//    bit-identical across kernels (is_best float-equality). DO NOT inline.
//  * JAX partitionable threefry; composite key (m<<16)|(65535-n), distinct.
//  * Inside-anchor set == 9 runtime rectangles (R8-verified vs k_out's ins).
//
// Changes vs R8 (pass, 156 us; k_sub3 46 us latency-bound):
//  * k_fuse: compact candidate lists + global 256-bin hist (R2 machinery,
//    exonerated by R5/R6 bisect); priof/priob arrays deleted.
//  * k_select: 32 blocks, bin-pick + single gather pass + exact rank -> K*.
//  * k_out: folds the disable (recompute own key, compare K*). No full-N
//    selection sweeps anywhere.
// ---------------------------------------------------------------------------

#define B_   16
#define A_   9
#define H_   64
#define W_   64
#define HW_  (H_*W_)
#define N_   (HW_*A_)      // 36864
#define KG_  50
#define S0_  (B_*A_*HW_)   // labels elems
#define S1_  (B_*4*A_*HW_) // targets / in_w / out_w elems
#define NGTB_ (B_*KG_)     // k_gtmax blocks
#define CAP_  20480        // per-(batch,phase) candidate cap (max possible 18624)
#define NHIST_ (B_*2*256 + B_*2)   // hist + cnt ints to clear

typedef unsigned long long ull;

// base anchors from generate_anchors() (exact: all half-integers cancel)
__constant__ float c_base[A_][4] = {
  { -84.f,  -40.f,  99.f,  55.f},
  {-176.f,  -88.f, 191.f, 103.f},
  {-360.f, -184.f, 375.f, 199.f},
  { -56.f,  -56.f,  71.f,  71.f},
  {-120.f, -120.f, 135.f, 135.f},
  {-248.f, -248.f, 263.f, 263.f},
  { -36.f,  -80.f,  51.f,  95.f},
  { -80.f, -168.f,  95.f, 183.f},
  {-168.f, -344.f, 183.f, 359.f},
};

__device__ __forceinline__ void tf2x32(uint32_t k0, uint32_t k1,
                                       uint32_t x0, uint32_t x1,
                                       uint32_t& o0, uint32_t& o1) {
  const uint32_t ks2 = k0 ^ k1 ^ 0x1BD11BDAu;
  uint32_t ks[3] = {k0, k1, ks2};
  x0 += ks[0]; x1 += ks[1];
  const int R[2][4] = {{13,15,26,6},{17,29,16,24}};
  #pragma unroll
  for (int i = 0; i < 5; i++) {
    #pragma unroll
    for (int j = 0; j < 4; j++) {
      x0 += x1;
      int r = R[i & 1][j];
      x1 = (x1 << r) | (x1 >> (32 - r));
      x1 ^= x0;
    }
    x0 += ks[(i + 1) % 3];
    x1 += ks[(i + 2) % 3] + (uint32_t)(i + 1);
  }
  o0 = x0; o1 = x1;
}

// ---------------------------------------------------------------------------
// Shared noinline numerics: single compiled copy each => cross-kernel
// bit-identity by construction. contract(off) as belt-and-braces.
__device__ __attribute__((noinline))
float box_area_f(float x1, float y1, float x2, float y2) {
#pragma clang fp contract(off)
  return (x2 - x1 + 1.f) * (y2 - y1 + 1.f);
}

__device__ __attribute__((noinline))
float iou_core(float ax1, float ay1, float ax2, float ay2, float aarea,
               float gx1, float gy1, float gx2, float gy2, float garea) {
#pragma clang fp contract(off)
  float ix = fmaxf(fminf(ax2, gx2) - fmaxf(ax1, gx1) + 1.f, 0.f);
  float iy = fmaxf(fminf(ay2, gy2) - fmaxf(ay1, gy1) + 1.f, 0.f);
  float inter = ix * iy;
  return inter / (aarea + garea - inter);
}

// ---------------------------------------------------------------------------
// K1: gt_max — one block per (b,gt), pruned to overlap∩inside rectangle.
// Block 0: threefry keys. Blocks 0..31: clear cnt+hist (stream-ordered
// before k_fuse's atomics).
__global__ __launch_bounds__(256) void k_gtmax(const float* __restrict__ gtb,
                                               const float* __restrict__ iminfo,
                                               float* __restrict__ gt_max,
                                               uint32_t* __restrict__ keys,
                                               int* __restrict__ cnt_hist) {
  const int b = blockIdx.x / KG_;
  const int g = blockIdx.x % KG_;
  const int tid = threadIdx.x;
  if (blockIdx.x == 0 && tid < B_) {
    uint32_t k0, k1, kf0, kf1, kb0, kb1;
    tf2x32(0u, 42u, 0u, (uint32_t)tid, k0, k1);  // split(root,16)[b]
    tf2x32(k0, k1, 0u, 0u, kf0, kf1);            // kf
    tf2x32(k0, k1, 0u, 1u, kb0, kb1);            // kb
    keys[tid * 4 + 0] = kf0;
    keys[tid * 4 + 1] = kf1;
    keys[tid * 4 + 2] = kb0;
    keys[tid * 4 + 3] = kb1;
  }
  if (blockIdx.x < 32) {
    const int per = (NHIST_ + 31) / 32;
    const int base = blockIdx.x * per;
    const int lim = min(base + per, NHIST_);
    for (int i = base + tid; i < lim; i += 256) cnt_hist[i] = 0;
  }
  const float* gp = gtb + (b * KG_ + g) * 5;
  const float gx1 = gp[0], gy1 = gp[1], gx2 = gp[2], gy2 = gp[3];
  const float garea = box_area_f(gx1, gy1, gx2, gy2);
  const float imh = iminfo[0], imw = iminfo[1];
  float best = 0.f;
  for (int a = 0; a < A_; a++) {
    const float bx1 = c_base[a][0], by1 = c_base[a][1];
    const float bx2 = c_base[a][2], by2 = c_base[a][3];
    const float aarea = box_area_f(bx1, by1, bx2, by2);  // == shifted (exact ints)
    int xlo = max(0, (int)ceilf(-bx1 / 16.f));
    int xhi = min(W_ - 1, (int)ceilf((imw - bx2) / 16.f) - 1);
    int ylo = max(0, (int)ceilf(-by1 / 16.f));
    int yhi = min(H_ - 1, (int)ceilf((imh - by2) / 16.f) - 1);
    xlo = max(xlo, (int)floorf((gx1 - 1.f - bx2) / 16.f));
    xhi = min(xhi, (int)ceilf((gx2 + 1.f - bx1) / 16.f));
    ylo = max(ylo, (int)floorf((gy1 - 1.f - by2) / 16.f));
    yhi = min(yhi, (int)ceilf((gy2 + 1.f - by1) / 16.f));
    const int nx = xhi - xlo + 1, ny = yhi - ylo + 1;
    if (nx <= 0 || ny <= 0) continue;
    const int lw = (nx <= 1) ? 0 : (32 - __clz(nx - 1));  // 2^lw >= nx
    const int tot = ny << lw;
    const int mask = (1 << lw) - 1;
    for (int t = tid; t < tot; t += 256) {
      const int xi = t & mask;
      if (xi >= nx) continue;
      const int x = xlo + xi;
      const int y = ylo + (t >> lw);
      const float sx = 16.f * (float)x, sy = 16.f * (float)y;
      best = fmaxf(best, iou_core(bx1 + sx, by1 + sy, bx2 + sx, by2 + sy,
                                  aarea, gx1, gy1, gx2, gy2, garea));
    }
  }
  best = fmaxf(best, __shfl_xor(best, 32));
  best = fmaxf(best, __shfl_xor(best, 16));
  best = fmaxf(best, __shfl_xor(best, 8));
  best = fmaxf(best, __shfl_xor(best, 4));
  best = fmaxf(best, __shfl_xor(best, 2));
  best = fmaxf(best, __shfl_xor(best, 1));
  __shared__ float sw[4];
  if ((tid & 63) == 0) sw[tid >> 6] = best;
  __syncthreads();
  if (tid == 0)
    gt_max[b * KG_ + g] = fmaxf(fmaxf(sw[0], sw[1]), fmaxf(sw[2], sw[3]));
}

// ---------------------------------------------------------------------------
// K2: fused labels over the compacted inside-anchor space + candidate
// compaction + 256-bin hist of m>>15. grid (144, B_): each thread handles
// at most ONE compacted index (144*256 >= N_ >= C).
__global__ __launch_bounds__(256) void k_fuse(const float* __restrict__ gtb,
                                              const float* __restrict__ iminfo,
                                              const float* __restrict__ gt_max,
                                              const uint32_t* __restrict__ keys,
                                              float* __restrict__ lbl,
                                              int* __restrict__ amax,
                                              ull* __restrict__ cand,
                                              int* __restrict__ cnt,
                                              int* __restrict__ hist) {
  __shared__ float sgx1[KG_], sgy1[KG_], sgx2[KG_], sgy2[KG_], sga[KG_], sgm[KG_];
  __shared__ int s_xlo[A_], s_ylo[A_], s_nx[A_], s_pre[A_ + 1];
  __shared__ uint32_t s_k[4];
  __shared__ int s_num[2], s_base[2];
  const int b = blockIdx.y;
  const int tid = threadIdx.x;
  if (tid < KG_) {
    const float* g = gtb + (b * KG_ + tid) * 5;
    float x1 = g[0], y1 = g[1], x2 = g[2], y2 = g[3];
    sgx1[tid] = x1; sgy1[tid] = y1; sgx2[tid] = x2; sgy2[tid] = y2;
    sga[tid] = box_area_f(x1, y1, x2, y2);
    float gm = gt_max[b * KG_ + tid];
    sgm[tid] = (gm == 0.f) ? 1e-5f : gm;
  }
  if (tid < 4) s_k[tid] = keys[b * 4 + tid];
  if (tid < 2) s_num[tid] = 0;
  if (tid < A_) {
    const float imh = iminfo[0], imw = iminfo[1];
    const float bx1 = c_base[tid][0], by1 = c_base[tid][1];
    const float bx2 = c_base[tid][2], by2 = c_base[tid][3];
    int xlo = max(0, (int)ceilf(-bx1 / 16.f));
    int xhi = min(W_ - 1, (int)ceilf((imw - bx2) / 16.f) - 1);
    int ylo = max(0, (int)ceilf(-by1 / 16.f));
    int yhi = min(H_ - 1, (int)ceilf((imh - by2) / 16.f) - 1);
    int nx = max(0, xhi - xlo + 1), ny = max(0, yhi - ylo + 1);
    s_xlo[tid] = xlo; s_ylo[tid] = ylo; s_nx[tid] = nx;
    s_pre[tid + 1] = nx * ny;
  }
  __syncthreads();
  if (tid == 0) {
    s_pre[0] = 0;
    for (int a = 0; a < A_; a++) s_pre[a + 1] += s_pre[a];
  }
  __syncthreads();
  const int C = s_pre[A_];
  const int t = blockIdx.x * 256 + tid;

  bool act = false;
  int p = 0, lpos = 0, n = 0;
  uint32_t m = 0;
  if (t < C) {
    int a = 0;
    while (t >= s_pre[a + 1]) a++;
    const int idx = t - s_pre[a];
    const int nx = s_nx[a];
    const int y = s_ylo[a] + idx / nx;
    const int x = s_xlo[a] + (idx - (idx / nx) * nx);
    n = (y * W_ + x) * A_ + a;
    const float sx = 16.f * (float)x, sy = 16.f * (float)y;
    const float ax1 = c_base[a][0] + sx, ay1 = c_base[a][1] + sy;
    const float ax2 = c_base[a][2] + sx, ay2 = c_base[a][3] + sy;
    const float aarea = box_area_f(c_base[a][0], c_base[a][1],
                                   c_base[a][2], c_base[a][3]);  // == shifted
    float mo = -1.f;
    int bidx = 0;
    bool best = false;
    for (int k = 0; k < KG_; k++) {
      float ovr = iou_core(ax1, ay1, ax2, ay2, aarea,
                           sgx1[k], sgy1[k], sgx2[k], sgy2[k], sga[k]);
      if (ovr > mo) { mo = ovr; bidx = k; }    // first-argmax (matches jnp)
      best = best || (ovr == sgm[k]);
    }
    float l = -1.f;
    if (mo < 0.3f) l = 0.f;
    if (best || mo >= 0.7f) l = 1.f;
    lbl[(size_t)b * N_ + n] = l;
    amax[(size_t)b * N_ + n] = bidx;
    if (l >= 0.f) {
      act = true;
      p = (l == 1.f) ? 0 : 1;
      uint32_t y0, y1;
      tf2x32(s_k[2 * p], s_k[2 * p + 1], 0u, (uint32_t)n, y0, y1);
      m = (y0 ^ y1) >> 9;
      lpos = atomicAdd(&s_num[p], 1);
    }
  }
  __syncthreads();
  if (tid < 2 && s_num[tid] > 0)
    s_base[tid] = atomicAdd(&cnt[b * 2 + tid], s_num[tid]);
  __syncthreads();
  if (act) {
    cand[(size_t)(b * 2 + p) * CAP_ + s_base[p] + lpos] =
        ((ull)m << 16) | (ull)(65535 - n);
    atomicAdd(&hist[(b * 2 + p) * 256 + (int)(m >> 15)], 1);
  }
}

// ---------------------------------------------------------------------------
// K3: per-(b,phase) cutoff K*. Serial bin-pick (R7-verified) + one gather
// pass over the compact list + exact in-LDS rank. 32 blocks.
__global__ __launch_bounds__(256) void k_select(const ull* __restrict__ cand,
                                                const int* __restrict__ cnt,
                                                const int* __restrict__ hist,
                                                ull* __restrict__ Kstar,
                                                float* __restrict__ uw) {
  const int b = blockIdx.x >> 1, p = blockIdx.x & 1;
  const int tid = threadIdx.x;
  __shared__ ull s_keys[2048];
  __shared__ int s_bin, s_r, s_n;
  const int cf = cnt[b * 2 + 0], cb = cnt[b * 2 + 1];
  const int limit = (p == 0) ? 128 : 256 - min(cf, 128);
  const int c = (p == 0) ? cf : cb;
  if (p == 1 && tid == 0) {
    int kf = min(cf, 128);
    int kb = min(cb, 256 - kf);
    uw[b] = 1.f / (float)(kf + kb);
  }
  if (c <= limit) {
    if (tid == 0) Kstar[b * 2 + p] = 0ull;   // keep all (keys always > 0)
    return;
  }
  if (tid == 0) {
    const int* Hh = hist + (b * 2 + p) * 256;
    int acc = 0, bin = 255, r = 0;
    for (; bin >= 0; bin--) {
      int hv = Hh[bin];
      if (acc + hv >= limit) { r = limit - acc; break; }
      acc += hv;
    }
    s_bin = bin; s_r = r; s_n = 0;
  }
  __syncthreads();
  const uint32_t bin0 = (uint32_t)s_bin;
  const int r0 = s_r;                        // 1-based rank within bin
  const ull* C = cand + (size_t)(b * 2 + p) * CAP_;
  for (int i = tid; i < c; i += 256) {
    ull k = C[i];
    if ((uint32_t)(k >> 31) == bin0) {       // key bits 31..38 == m>>15
      int pos = atomicAdd(&s_n, 1);
      if (pos < 2048) s_keys[pos] = k;
    }
  }
  __syncthreads();
  const int s = min(s_n, 2048);
  for (int j = tid; j < s; j += 256) {
    ull kj = s_keys[j];
    int rank = 0;
    for (int q = 0; q < s; q++) rank += (s_keys[q] > kj) ? 1 : 0;
    if (rank == r0 - 1) Kstar[b * 2 + p] = kj;   // unique writer (keys distinct)
  }
}

// ---------------------------------------------------------------------------
// K4: outputs with folded disable (recompute own key, compare K*).
__global__ __launch_bounds__(256) void k_out(const float* __restrict__ gtb,
                                             const float* __restrict__ iminfo,
                                             const float* __restrict__ lbl,
                                             const int* __restrict__ amax,
                                             const ull* __restrict__ Kstar,
                                             const float* __restrict__ uw,
                                             const uint32_t* __restrict__ keys,
                                             float* __restrict__ out) {
  const int t = blockIdx.x * 256 + threadIdx.x;  // 0 .. S0_-1 exactly
  const int w = t & 63;
  const int h = (t >> 6) & 63;
  const int a = (t >> 12) % A_;
  const int b = t / (A_ * HW_);
  const int n = (h * W_ + w) * A_ + a;

  const float ax1 = c_base[a][0] + 16.f * (float)w;
  const float ay1 = c_base[a][1] + 16.f * (float)h;
  const float ax2 = c_base[a][2] + 16.f * (float)w;
  const float ay2 = c_base[a][3] + 16.f * (float)h;
  const float imh = iminfo[0], imw = iminfo[1];
  const bool ins = (ax1 >= 0.f) && (ay1 >= 0.f) && (ax2 < imw) && (ay2 < imh);

  float l = ins ? lbl[(size_t)b * N_ + n] : -1.f;
  if (ins && l >= 0.f) {                      // folded disable
    const int p = (l == 1.f) ? 0 : 1;
    uint32_t y0, y1;
    tf2x32(keys[b * 4 + 2 * p], keys[b * 4 + 2 * p + 1], 0u, (uint32_t)n, y0, y1);
    ull key = ((ull)((y0 ^ y1) >> 9) << 16) | (ull)(65535 - n);
    if (key < Kstar[b * 2 + p]) l = -1.f;
  }

  // labels: (B,1,A*H,W)
  out[(size_t)b * (A_ * HW_) + a * HW_ + h * W_ + w] = ins ? l : 0.f;

  // targets
  float tx = 0.f, ty = 0.f, tw = 0.f, th = 0.f;
  if (ins) {
    const int g = amax[(size_t)b * N_ + n];
    const float* gp = gtb + ((size_t)b * KG_ + g) * 5;
    float aw = ax2 - ax1 + 1.f, ah = ay2 - ay1 + 1.f;
    float acx = ax1 + 0.5f * (aw - 1.f), acy = ay1 + 0.5f * (ah - 1.f);
    float gw = gp[2] - gp[0] + 1.f, gh = gp[3] - gp[1] + 1.f;
    float gcx = gp[0] + 0.5f * (gw - 1.f), gcy = gp[1] + 0.5f * (gh - 1.f);
    tx = (gcx - acx) / aw;
    ty = (gcy - acy) / ah;
    tw = logf(gw / aw);
    th = logf(gh / ah);
  }
  float* o1 = out + S0_;
  const size_t toff = (size_t)b * (4 * A_ * HW_) + (4 * a) * HW_ + h * W_ + w;
  o1[toff]           = tx;
  o1[toff + HW_]     = ty;
  o1[toff + 2 * HW_] = tw;
  o1[toff + 3 * HW_] = th;

  const float inw = (ins && l == 1.f) ? 1.f : 0.f;
  const float oww = (ins && l >= 0.f) ? uw[b] : 0.f;
  float* o2 = out + S0_ + S1_;
  o2[toff] = inw; o2[toff + HW_] = inw; o2[toff + 2 * HW_] = inw; o2[toff + 3 * HW_] = inw;
  float* o3 = out + S0_ + 2 * (size_t)S1_;
  o3[toff] = oww; o3[toff + HW_] = oww; o3[toff + 2 * HW_] = oww; o3[toff + 3 * HW_] = oww;
}

// ---------------------------------------------------------------------------
extern "C" void kernel_launch(void* const* d_in, const int* in_sizes, int n_in,
                              void* d_out, int out_size, void* d_ws, size_t ws_size,
                              hipStream_t stream) {
  const float* gtb = (const float*)d_in[1];     // gt_boxes (B,50,5)
  const float* iminfo = (const float*)d_in[2];  // im_info  (B,2)
  float* out = (float*)d_out;

  // workspace layout (~10.1 MB); every segment size is a multiple of 8 bytes.
  float* lbl = (float*)d_ws;                        // B*N
  int* amax = (int*)(lbl + (size_t)B_ * N_);        // B*N
  float* gt_max = (float*)(amax + (size_t)B_ * N_); // B*KG (3200 B)
  float* uw = gt_max + B_ * KG_;                    // B    (64 B)
  uint32_t* keys = (uint32_t*)(uw + B_);            // B*4  (256 B)
  int* cnt = (int*)(keys + B_ * 4);                 // B*2  (128 B)
  int* hist = cnt + B_ * 2;                         // B*2*256 (32 KB)
  ull* Kstar = (ull*)(hist + B_ * 2 * 256);         // B*2  (256 B)
  ull* cand = Kstar + B_ * 2;                       // B*2*CAP (5.2 MB)

  k_gtmax<<<NGTB_, 256, 0, stream>>>(gtb, iminfo, gt_max, keys, cnt);
  k_fuse<<<dim3(144, B_), 256, 0, stream>>>(gtb, iminfo, gt_max, keys,
                                            lbl, amax, cand, cnt, hist);
  k_select<<<B_ * 2, 256, 0, stream>>>(cand, cnt, hist, Kstar, uw);
  k_out<<<S0_ / 256, 256, 0, stream>>>(gtb, iminfo, lbl, amax, Kstar, uw,
                                       keys, out);
}